// Round 5
// baseline (284.996 us; speedup 1.0000x reference)
//
#include <hip/hip_runtime.h>
#include <hip/hip_bf16.h>

#define EPS 1e-5f

typedef __attribute__((ext_vector_type(8))) short bf16x8;
typedef __attribute__((ext_vector_type(4))) float f32x4;

__device__ __forceinline__ ushort f2bf(float x) {
  __hip_bfloat16 h = __float2bfloat16(x);
  return *reinterpret_cast<ushort*>(&h);
}
__device__ __forceinline__ float bf2f(ushort u) {
  __hip_bfloat16 h;
  *reinterpret_cast<ushort*>(&h) = u;
  return __bfloat162float(h);
}

// ---------------- k1s: layer1 raw stats (bias cancels through BN) ----------------
// grid 256 (8 rows each), 256 threads (4 cols each).
__global__ __launch_bounds__(256) void k1s(const float* __restrict__ G,
                                           const float* __restrict__ W1,
                                           float* __restrict__ psum,
                                           float* __restrict__ psqs) {
  int r0 = blockIdx.x * 8;
  int c = threadIdx.x * 4;
  float w[4][8];
#pragma unroll
  for (int q = 0; q < 4; ++q)
#pragma unroll
    for (int k = 0; k < 8; ++k) w[q][k] = W1[(c + q) * 8 + k];
  float s[4] = {}, ss[4] = {};
  for (int r = 0; r < 8; ++r) {
    const float4 g0 = *(const float4*)&G[(size_t)(r0 + r) * 8];
    const float4 g1 = *(const float4*)&G[(size_t)(r0 + r) * 8 + 4];
    float gr[8] = {g0.x, g0.y, g0.z, g0.w, g1.x, g1.y, g1.z, g1.w};
#pragma unroll
    for (int q = 0; q < 4; ++q) {
      float acc = 0.f;
#pragma unroll
      for (int k = 0; k < 8; ++k) acc += gr[k] * w[q][k];
      s[q] += acc;
      ss[q] += acc * acc;
    }
  }
#pragma unroll
  for (int q = 0; q < 4; ++q) {
    psum[blockIdx.x * 1024 + c + q] = s[q];
    psqs[blockIdx.x * 1024 + c + q] = ss[q];
  }
}

// ---------------- kfin: totals/partials -> scale/shift ----------------
__global__ __launch_bounds__(256) void kfin(const float* __restrict__ ps,
                                            const float* __restrict__ qs,
                                            const float* __restrict__ g,
                                            const float* __restrict__ be,
                                            float* __restrict__ scale,
                                            float* __restrict__ shift,
                                            int npart, int stride, int nactive) {
  int j = blockIdx.x * 256 + threadIdx.x;
  if (j >= nactive) return;
  float s = 0.f, ss = 0.f;
  for (int p = 0; p < npart; ++p) {
    s += ps[p * stride + j];
    ss += qs[p * stride + j];
  }
  float mu = s * (1.f / 2048.f);
  float var = ss * (1.f / 2048.f) - mu * mu;
  float sc = g[j] * rsqrtf(var + EPS);
  scale[j] = sc;
  shift[j] = be[j] - mu * sc;
}

// ---------------- k1c: recompute raw Y1, BN+ReLU, split to bf16 hi/lo ----------------
__global__ __launch_bounds__(256) void k1c(
    const float* __restrict__ G, const float* __restrict__ W1,
    const float* __restrict__ scale1, const float* __restrict__ shift1,
    ushort* __restrict__ X1hi, ushort* __restrict__ X1lo) {
  int r0 = blockIdx.x * 8;
  int c = threadIdx.x * 4;
  float w[4][8];
#pragma unroll
  for (int q = 0; q < 4; ++q)
#pragma unroll
    for (int k = 0; k < 8; ++k) w[q][k] = W1[(c + q) * 8 + k];
  float sc[4], sh[4];
#pragma unroll
  for (int q = 0; q < 4; ++q) {
    sc[q] = scale1[c + q];
    sh[q] = shift1[c + q];
  }
  for (int r = 0; r < 8; ++r) {
    const float4 g0 = *(const float4*)&G[(size_t)(r0 + r) * 8];
    const float4 g1 = *(const float4*)&G[(size_t)(r0 + r) * 8 + 4];
    float gr[8] = {g0.x, g0.y, g0.z, g0.w, g1.x, g1.y, g1.z, g1.w};
    ushort hs[4], ls[4];
#pragma unroll
    for (int q = 0; q < 4; ++q) {
      float acc = 0.f;
#pragma unroll
      for (int k = 0; k < 8; ++k) acc += gr[k] * w[q][k];
      float x = fmaxf(0.f, acc * sc[q] + sh[q]);
      ushort h = f2bf(x);
      float hf = bf2f(h);
      hs[q] = h;
      ls[q] = f2bf(x - hf);
    }
    size_t o = (size_t)(r0 + r) * 1024 + c;
    *(ushort4*)&X1hi[o] = make_ushort4(hs[0], hs[1], hs[2], hs[3]);
    *(ushort4*)&X1lo[o] = make_ushort4(ls[0], ls[1], ls[2], ls[3]);
  }
}

// ---------------- k2: MFMA bf16 hi/lo GEMM2 + fused column-stat atomics ----------------
__global__ __launch_bounds__(256) void k2_mfma(
    const ushort* __restrict__ X1hi, const ushort* __restrict__ X1lo,
    const float* __restrict__ W2, float* __restrict__ Y2,
    float* __restrict__ sA2, float* __restrict__ qA2) {
  __shared__ short lAhi[128 * 64], lAlo[128 * 64];
  __shared__ short lBhi[64 * 64], lBlo[64 * 64];
  int id = blockIdx.x;
  int xcd = id & 7, slot = id >> 3;
  int g = slot >> 4, wi = slot & 15;
  int bx = (xcd & 3) * 4 + (wi & 3);
  int by = ((xcd >> 2) * 2 + g) * 4 + (wi >> 2);
  int b0 = bx * 128, j0 = by * 64;
  int tid = threadIdx.x;
  int lane = tid & 63, wave = tid >> 6;
  int wm = wave >> 1, wn = wave & 1;
  int brow = tid >> 2, bkq = tid & 3;
  f32x4 acc[4][2] = {};
  for (int k0 = 0; k0 < 1024; k0 += 64) {
#pragma unroll
    for (int i = 0; i < 4; ++i) {
      int chunk = tid * 4 + i;
      int row = chunk >> 3, c = chunk & 7;
      size_t go = (size_t)(b0 + row) * 1024 + k0 + c * 8;
      bf16x8 vh = *(const bf16x8*)&X1hi[go];
      bf16x8 vl = *(const bf16x8*)&X1lo[go];
      int d = row * 64 + ((c ^ (row & 7)) << 3);
      *(bf16x8*)&lAhi[d] = vh;
      *(bf16x8*)&lAlo[d] = vl;
    }
    {
      const float* src = &W2[(size_t)(j0 + brow) * 1024 + k0 + bkq * 16];
      float4 f0 = *(const float4*)(src);
      float4 f1 = *(const float4*)(src + 4);
      float4 f2 = *(const float4*)(src + 8);
      float4 f3 = *(const float4*)(src + 12);
      float v[16] = {f0.x, f0.y, f0.z, f0.w, f1.x, f1.y, f1.z, f1.w,
                     f2.x, f2.y, f2.z, f2.w, f3.x, f3.y, f3.z, f3.w};
      bf16x8 h0, l0, h1, l1;
#pragma unroll
      for (int e = 0; e < 8; ++e) {
        ushort h = f2bf(v[e]);
        h0[e] = (short)h;
        l0[e] = (short)f2bf(v[e] - bf2f(h));
      }
#pragma unroll
      for (int e = 0; e < 8; ++e) {
        ushort h = f2bf(v[8 + e]);
        h1[e] = (short)h;
        l1[e] = (short)f2bf(v[8 + e] - bf2f(h));
      }
      int c0 = bkq * 2, c1 = bkq * 2 + 1;
      int d0 = brow * 64 + ((c0 ^ (brow & 7)) << 3);
      int d1 = brow * 64 + ((c1 ^ (brow & 7)) << 3);
      *(bf16x8*)&lBhi[d0] = h0;
      *(bf16x8*)&lBlo[d0] = l0;
      *(bf16x8*)&lBhi[d1] = h1;
      *(bf16x8*)&lBlo[d1] = l1;
    }
    __syncthreads();
#pragma unroll
    for (int kk = 0; kk < 2; ++kk) {
      bf16x8 ah[4], al[4], bh[2], bl[2];
#pragma unroll
      for (int mi = 0; mi < 4; ++mi) {
        int r = wm * 64 + mi * 16 + (lane & 15);
        int cc = (((kk << 2) + (lane >> 4)) ^ (r & 7)) << 3;
        ah[mi] = *(const bf16x8*)&lAhi[r * 64 + cc];
        al[mi] = *(const bf16x8*)&lAlo[r * 64 + cc];
      }
#pragma unroll
      for (int ni = 0; ni < 2; ++ni) {
        int r = wn * 32 + ni * 16 + (lane & 15);
        int cc = (((kk << 2) + (lane >> 4)) ^ (r & 7)) << 3;
        bh[ni] = *(const bf16x8*)&lBhi[r * 64 + cc];
        bl[ni] = *(const bf16x8*)&lBlo[r * 64 + cc];
      }
#pragma unroll
      for (int mi = 0; mi < 4; ++mi)
#pragma unroll
        for (int ni = 0; ni < 2; ++ni) {
          acc[mi][ni] = __builtin_amdgcn_mfma_f32_16x16x32_bf16(
              ah[mi], bh[ni], acc[mi][ni], 0, 0, 0);
          acc[mi][ni] = __builtin_amdgcn_mfma_f32_16x16x32_bf16(
              al[mi], bh[ni], acc[mi][ni], 0, 0, 0);
          acc[mi][ni] = __builtin_amdgcn_mfma_f32_16x16x32_bf16(
              ah[mi], bl[ni], acc[mi][ni], 0, 0, 0);
        }
    }
    __syncthreads();
  }
  // raw Y2 write (no bias — cancels through BN)
#pragma unroll
  for (int mi = 0; mi < 4; ++mi)
#pragma unroll
    for (int ni = 0; ni < 2; ++ni) {
      int col = j0 + wn * 32 + ni * 16 + (lane & 15);
#pragma unroll
      for (int r = 0; r < 4; ++r) {
        int row = b0 + wm * 64 + mi * 16 + (lane >> 4) * 4 + r;
        Y2[(size_t)row * 1024 + col] = acc[mi][ni][r];
      }
    }
  // fused column stats: per-thread 16 rows -> shfl reduce -> atomic
#pragma unroll
  for (int ni = 0; ni < 2; ++ni) {
    float s = 0.f, q = 0.f;
#pragma unroll
    for (int mi = 0; mi < 4; ++mi)
#pragma unroll
      for (int r = 0; r < 4; ++r) {
        float v = acc[mi][ni][r];
        s += v;
        q += v * v;
      }
    s += __shfl_xor(s, 16);
    q += __shfl_xor(q, 16);
    s += __shfl_xor(s, 32);
    q += __shfl_xor(q, 32);
    if ((lane >> 4) == 0) {
      int col = j0 + wn * 32 + ni * 16 + lane;
      atomicAdd(&sA2[col], s);
      atomicAdd(&qA2[col], q);
    }
  }
}

// ---------------- k4: GEMM3 split-K, fused BN2+ReLU, atomic into Y3 ----------------
// tile 32(M) x 64(N), K-slice 256, grid (64,3,4). LDS transposed [k][row].
__global__ __launch_bounds__(256) void k4_gemm3(
    const float* __restrict__ Y2, const float* __restrict__ scale2,
    const float* __restrict__ shift2, const float* __restrict__ W3,
    float* __restrict__ Y3) {
  __shared__ float As[16][34], Bs[16][68];
  int b0 = blockIdx.x * 32, j0 = blockIdx.y * 64, kz = blockIdx.z;
  int tid = threadIdx.x;
  int tx = tid & 15, ty = tid >> 4;
  int arow = tid >> 3, akq = (tid & 7) * 2;
  int brow = tid >> 2, bkq = (tid & 3) * 4;
  int jb = j0 + brow;
  float c[2][4] = {};
  int kbase = kz * 256;
  for (int k0 = kbase; k0 < kbase + 256; k0 += 16) {
    float2 sc = *(const float2*)&scale2[k0 + akq];
    float2 sh = *(const float2*)&shift2[k0 + akq];
    float2 av = *(const float2*)&Y2[(size_t)(b0 + arow) * 1024 + k0 + akq];
    As[akq + 0][arow] = fmaxf(0.f, av.x * sc.x + sh.x);
    As[akq + 1][arow] = fmaxf(0.f, av.y * sc.y + sh.y);
    float4 bv = make_float4(0.f, 0.f, 0.f, 0.f);
    if (jb < 150) bv = *(const float4*)&W3[(size_t)jb * 1024 + k0 + bkq];
    Bs[bkq + 0][brow] = bv.x;
    Bs[bkq + 1][brow] = bv.y;
    Bs[bkq + 2][brow] = bv.z;
    Bs[bkq + 3][brow] = bv.w;
    __syncthreads();
#pragma unroll
    for (int k = 0; k < 16; ++k) {
      float2 a = *(const float2*)&As[k][ty * 2];
      float4 b = *(const float4*)&Bs[k][tx * 4];
      c[0][0] += a.x * b.x; c[0][1] += a.x * b.y;
      c[0][2] += a.x * b.z; c[0][3] += a.x * b.w;
      c[1][0] += a.y * b.x; c[1][1] += a.y * b.y;
      c[1][2] += a.y * b.z; c[1][3] += a.y * b.w;
    }
    __syncthreads();
  }
#pragma unroll
  for (int i = 0; i < 2; ++i) {
    int r = b0 + ty * 2 + i;
#pragma unroll
    for (int jx = 0; jx < 4; ++jx) {
      int jj = j0 + tx * 4 + jx;
      if (jj < 150) atomicAdd(&Y3[(size_t)r * 150 + jj], c[i][jx]);
    }
  }
}

// ---------------- k5s: raw Y3 column-stat partials ----------------
__global__ __launch_bounds__(256) void k5s(const float* __restrict__ Y3,
                                           float* __restrict__ ps,
                                           float* __restrict__ qs) {
  int r0 = blockIdx.x * 8;
  int j = threadIdx.x;
  if (j >= 150) return;
  float s = 0.f, q = 0.f;
  for (int r = 0; r < 8; ++r) {
    float v = Y3[(size_t)(r0 + r) * 150 + j];
    s += v;
    q += v * v;
  }
  ps[blockIdx.x * 160 + j] = s;
  qs[blockIdx.x * 160 + j] = q;
}

// ---------------- k6a: BN3+ReLU + conv chain -> lorentz pre-struct ----------------
__global__ __launch_bounds__(256) void k6a(
    const float* __restrict__ Y3, const float* __restrict__ scale3,
    const float* __restrict__ shift3, const float* __restrict__ ct1_w,
    const float* __restrict__ ct1_b, const float* __restrict__ ct2_w,
    const float* __restrict__ ct2_b, const float* __restrict__ ct3_w,
    const float* __restrict__ ct3_b, const float* __restrict__ cf_w,
    const float* __restrict__ cf_b, float* __restrict__ Spre) {
  __shared__ float wt1[32], wb1[4], wt2[80], wb2[4], w3f[20];
  __shared__ float cfb2s;
  __shared__ float h0p[4][160];
  __shared__ float hA[4][4][308];
  __shared__ float hB[4][4][308];
  __shared__ float Srow[4][304];
  int tid = threadIdx.x;
  if (tid < 32) wt1[tid] = ct1_w[tid];
  else if (tid < 36) wb1[tid - 32] = ct1_b[tid - 32];
  else if (tid < 116) wt2[tid - 36] = ct2_w[tid - 36];
  else if (tid < 120) wb2[tid - 116] = ct2_b[tid - 116];
  else if (tid < 140) {
    int i = (tid - 120) / 5, j = (tid - 120) % 5;
    float s = 0.f;
#pragma unroll
    for (int p = 0; p < 4; ++p) s += cf_w[p] * ct3_w[(i * 4 + p) * 5 + j];
    w3f[tid - 120] = s;
  } else if (tid == 140) {
    float s = cf_b[0];
#pragma unroll
    for (int p = 0; p < 4; ++p) s += cf_w[p] * ct3_b[p];
    cfb2s = s;
  }
  int w = tid >> 6;
  int lane = tid & 63;
  int r = blockIdx.x * 4 + w;
  __syncthreads();
  for (int i = lane; i < 160; i += 64) {
    int k = i - 2;
    float v = 0.f;
    if (k >= 0 && k < 150)
      v = fmaxf(0.f, Y3[(size_t)r * 150 + k] * scale3[k] + shift3[k]);
    h0p[w][i] = v;
  }
  if (lane < 8) {
    int z = (lane < 2) ? lane : (302 + lane - 2);
#pragma unroll
    for (int o = 0; o < 4; ++o) {
      hA[w][o][z] = 0.f;
      hB[w][o][z] = 0.f;
    }
  }
  __syncthreads();
  for (int t = lane; t < 300; t += 64) {
    int p1 = (t + 3) & 1;
    int base = (t + 3 - p1) >> 1;
    float x0 = h0p[w][2 + base];
    float x1 = h0p[w][1 + base];
    float x2 = h0p[w][base];
    float x3 = h0p[w][base - 1];
#pragma unroll
    for (int o = 0; o < 4; ++o) {
      float acc = wb1[o];
      acc += wt1[o * 8 + p1] * x0;
      acc += wt1[o * 8 + p1 + 2] * x1;
      acc += wt1[o * 8 + p1 + 4] * x2;
      acc += wt1[o * 8 + p1 + 6] * x3;
      hA[w][o][2 + t] = acc;
    }
  }
  __syncthreads();
  for (int t = lane; t < 300; t += 64) {
#pragma unroll
    for (int o = 0; o < 4; ++o) {
      float acc = wb2[o];
#pragma unroll
      for (int i = 0; i < 4; ++i)
#pragma unroll
        for (int j = 0; j < 5; ++j) acc += wt2[(i * 4 + o) * 5 + j] * hA[w][i][t + 4 - j];
      hB[w][o][2 + t] = acc;
    }
  }
  __syncthreads();
  for (int t = lane; t < 300; t += 64) {
    float acc = cfb2s;
#pragma unroll
    for (int i = 0; i < 4; ++i)
#pragma unroll
      for (int j = 0; j < 5; ++j) acc += w3f[i * 5 + j] * hB[w][i][t + 4 - j];
    Srow[w][t] = acc;
  }
  __syncthreads();
  for (int cc = lane; cc < 100; cc += 64) {
    float s0 = Srow[w][3 * cc], s1 = Srow[w][3 * cc + 1], s2 = Srow[w][3 * cc + 2];
    float4 p;
    p.x = s0 * s0;
    p.y = s1 * s1;
    p.z = s2 * s2;
    p.w = 0.f;
    *(float4*)&Spre[((size_t)r * 100 + cc) * 4] = p;
  }
}

// ---------------- k6b: lorentz, cc-split x4, wave-uniform scalar loads ----------------
__global__ __launch_bounds__(320) void k6b(const float* __restrict__ Spre,
                                           float* __restrict__ out) {
  int b = blockIdx.x;
  int l = threadIdx.x;
  float wl = 0.8f + (float)l * (1.0f / 300.0f);
  float w2l = wl * wl;
  float acc = 0.f;
  const float4* pp = (const float4*)&Spre[(size_t)b * 400] + blockIdx.y * 25;
#pragma unroll 5
  for (int cc = 0; cc < 25; ++cc) {
    float4 p = pp[cc];  // uniform addr -> scalar load
    float wp2 = p.x, s1sq = p.y, s2sq = p.z;
    float sub1 = s1sq - w2l;
    float denom = fmaf(sub1, sub1, w2l * s2sq);
    float inv = __builtin_amdgcn_rcpf(denom);
    float u = wp2 * inv;
    float tp = u * (wp2 + sub1);
    float tm = u * (wp2 - sub1);
    float n = 0.70710678f * __builtin_amdgcn_sqrtf(fmaxf(tp, 0.f));
    float np1 = n + 1.0f;
    float den2 = fmaf(np1, np1, 0.5f * fmaxf(tm, 0.f));
    acc = fmaf(4.0f * n, __builtin_amdgcn_rcpf(den2), acc);
  }
  if (l < 300) atomicAdd(&out[(size_t)b * 300 + l], acc);
}

extern "C" void kernel_launch(void* const* d_in, const int* in_sizes, int n_in,
                              void* d_out, int out_size, void* d_ws,
                              size_t ws_size, hipStream_t stream) {
  const float* G = (const float*)d_in[0];
  const float* w1 = (const float*)d_in[1];
  const float* g1 = (const float*)d_in[3];
  const float* be1 = (const float*)d_in[4];
  const float* w2 = (const float*)d_in[5];
  const float* g2 = (const float*)d_in[7];
  const float* be2 = (const float*)d_in[8];
  const float* w3 = (const float*)d_in[9];
  const float* g3 = (const float*)d_in[11];
  const float* be3 = (const float*)d_in[12];
  const float* ct1_w = (const float*)d_in[13];
  const float* ct1_b = (const float*)d_in[14];
  const float* ct2_w = (const float*)d_in[15];
  const float* ct2_b = (const float*)d_in[16];
  const float* ct3_w = (const float*)d_in[17];
  const float* ct3_b = (const float*)d_in[18];
  const float* cf_w = (const float*)d_in[19];
  const float* cf_b = (const float*)d_in[20];
  float* out = (float*)d_out;

  float* ws = (float*)d_ws;
  // [0, 2097152): Y2 (k2->k4) | psum1@0/psqs1@262144 (k1s->kfin1, dead by k2)
  //               | ps3@0/qs3@40960 (k5s->kfin3, after k4: Y2 dead)
  float* Y2 = ws;
  float* psum1 = ws;
  float* psqs1 = ws + 262144;
  float* ps3 = ws;
  float* qs3 = ws + 40960;
  // [2097152, 3145728): X1hi (k1c->k2) | Spre (k6a->k6b, after k2)
  ushort* X1hi = (ushort*)(ws + 2097152);
  float* Spre = ws + 2097152;
  // [3145728, 4194304): X1lo (k1c->k2) | Y3 @ tail (written by k4, after k2)
  ushort* X1lo = (ushort*)(ws + 3145728);
  float* Y3 = ws + 3887104;  // 307200 floats, tail of X1lo region
  // [4194304, ...): scale/shift (reused L1->L2->L3), sA2, qA2
  float* scaleX = ws + 4194304;
  float* shiftX = ws + 4195328;
  float* sA2 = ws + 4196352;
  float* qA2 = ws + 4197376;

  hipMemsetAsync(sA2, 0, 2048 * sizeof(float), stream);  // sA2+qA2
  hipMemsetAsync(out, 0, (size_t)out_size * sizeof(float), stream);

  k1s<<<256, 256, 0, stream>>>(G, w1, psum1, psqs1);
  kfin<<<4, 256, 0, stream>>>(psum1, psqs1, g1, be1, scaleX, shiftX, 256, 1024, 1024);
  k1c<<<256, 256, 0, stream>>>(G, w1, scaleX, shiftX, X1hi, X1lo);
  k2_mfma<<<256, 256, 0, stream>>>(X1hi, X1lo, w2, Y2, sA2, qA2);
  kfin<<<4, 256, 0, stream>>>(sA2, qA2, g2, be2, scaleX, shiftX, 1, 0, 1024);
  hipMemsetAsync(Y3, 0, 307200 * sizeof(float), stream);
  k4_gemm3<<<dim3(64, 3, 4), 256, 0, stream>>>(Y2, scaleX, shiftX, w3, Y3);
  k5s<<<256, 256, 0, stream>>>(Y3, ps3, qs3);
  kfin<<<1, 256, 0, stream>>>(ps3, qs3, g3, be3, scaleX, shiftX, 256, 160, 150);
  k6a<<<512, 256, 0, stream>>>(Y3, scaleX, shiftX, ct1_w, ct1_b, ct2_w, ct2_b,
                               ct3_w, ct3_b, cf_w, cf_b, Spre);
  k6b<<<dim3(2048, 4), 320, 0, stream>>>(Spre, out);
}

// Round 6
// 173.156 us; speedup vs baseline: 1.6459x; 1.6459x over previous
//
#include <hip/hip_runtime.h>
#include <hip/hip_bf16.h>

#define EPS 1e-5f

typedef __attribute__((ext_vector_type(8))) short bf16x8;
typedef __attribute__((ext_vector_type(4))) float f32x4;

__device__ __forceinline__ ushort f2bf(float x) {
  __hip_bfloat16 h = __float2bfloat16(x);
  return *reinterpret_cast<ushort*>(&h);
}
__device__ __forceinline__ float bf2f(ushort u) {
  __hip_bfloat16 h;
  *reinterpret_cast<ushort*>(&h) = u;
  return __bfloat162float(h);
}
__device__ __forceinline__ void bn_coef(float s, float q, float g, float be,
                                        float& sc, float& sh) {
  float mu = s * (1.f / 2048.f);
  float var = q * (1.f / 2048.f) - mu * mu;
  sc = g * rsqrtf(var + EPS);
  sh = be - mu * sc;
}

// ---------------- k1s: layer1 raw stats -> atomic accumulators ----------------
// grid 256 (8 rows each), 256 threads (4 cols each). Bias cancels through BN.
__global__ __launch_bounds__(256) void k1s(const float* __restrict__ G,
                                           const float* __restrict__ W1,
                                           float* __restrict__ sA1,
                                           float* __restrict__ qA1) {
  int r0 = blockIdx.x * 8;
  int c = threadIdx.x * 4;
  float w[4][8];
#pragma unroll
  for (int q = 0; q < 4; ++q)
#pragma unroll
    for (int k = 0; k < 8; ++k) w[q][k] = W1[(c + q) * 8 + k];
  float s[4] = {}, ss[4] = {};
  for (int r = 0; r < 8; ++r) {
    const float4 g0 = *(const float4*)&G[(size_t)(r0 + r) * 8];
    const float4 g1 = *(const float4*)&G[(size_t)(r0 + r) * 8 + 4];
    float gr[8] = {g0.x, g0.y, g0.z, g0.w, g1.x, g1.y, g1.z, g1.w};
#pragma unroll
    for (int q = 0; q < 4; ++q) {
      float acc = 0.f;
#pragma unroll
      for (int k = 0; k < 8; ++k) acc += gr[k] * w[q][k];
      s[q] += acc;
      ss[q] += acc * acc;
    }
  }
#pragma unroll
  for (int q = 0; q < 4; ++q) {
    atomicAdd(&sA1[c + q], s[q]);
    atomicAdd(&qA1[c + q], ss[q]);
  }
}

// ---------------- k1c: recompute raw Y1, inline BN1+ReLU, split bf16 hi/lo ----------------
__global__ __launch_bounds__(256) void k1c(
    const float* __restrict__ G, const float* __restrict__ W1,
    const float* __restrict__ sA1, const float* __restrict__ qA1,
    const float* __restrict__ g1, const float* __restrict__ be1,
    ushort* __restrict__ X1hi, ushort* __restrict__ X1lo) {
  int r0 = blockIdx.x * 8;
  int c = threadIdx.x * 4;
  float w[4][8];
#pragma unroll
  for (int q = 0; q < 4; ++q)
#pragma unroll
    for (int k = 0; k < 8; ++k) w[q][k] = W1[(c + q) * 8 + k];
  float sc[4], sh[4];
#pragma unroll
  for (int q = 0; q < 4; ++q)
    bn_coef(sA1[c + q], qA1[c + q], g1[c + q], be1[c + q], sc[q], sh[q]);
  for (int r = 0; r < 8; ++r) {
    const float4 g0 = *(const float4*)&G[(size_t)(r0 + r) * 8];
    const float4 g1v = *(const float4*)&G[(size_t)(r0 + r) * 8 + 4];
    float gr[8] = {g0.x, g0.y, g0.z, g0.w, g1v.x, g1v.y, g1v.z, g1v.w};
    ushort hs[4], ls[4];
#pragma unroll
    for (int q = 0; q < 4; ++q) {
      float acc = 0.f;
#pragma unroll
      for (int k = 0; k < 8; ++k) acc += gr[k] * w[q][k];
      float x = fmaxf(0.f, acc * sc[q] + sh[q]);
      ushort h = f2bf(x);
      float hf = bf2f(h);
      hs[q] = h;
      ls[q] = f2bf(x - hf);
    }
    size_t o = (size_t)(r0 + r) * 1024 + c;
    *(ushort4*)&X1hi[o] = make_ushort4(hs[0], hs[1], hs[2], hs[3]);
    *(ushort4*)&X1lo[o] = make_ushort4(ls[0], ls[1], ls[2], ls[3]);
  }
}

// ---------------- k2: MFMA bf16 hi/lo GEMM2 + fused column-stat atomics ----------------
__global__ __launch_bounds__(256) void k2_mfma(
    const ushort* __restrict__ X1hi, const ushort* __restrict__ X1lo,
    const float* __restrict__ W2, float* __restrict__ Y2,
    float* __restrict__ sA2, float* __restrict__ qA2) {
  __shared__ short lAhi[128 * 64], lAlo[128 * 64];
  __shared__ short lBhi[64 * 64], lBlo[64 * 64];
  int id = blockIdx.x;
  int xcd = id & 7, slot = id >> 3;
  int g = slot >> 4, wi = slot & 15;
  int bx = (xcd & 3) * 4 + (wi & 3);
  int by = ((xcd >> 2) * 2 + g) * 4 + (wi >> 2);
  int b0 = bx * 128, j0 = by * 64;
  int tid = threadIdx.x;
  int lane = tid & 63, wave = tid >> 6;
  int wm = wave >> 1, wn = wave & 1;
  int brow = tid >> 2, bkq = tid & 3;
  f32x4 acc[4][2] = {};
  for (int k0 = 0; k0 < 1024; k0 += 64) {
#pragma unroll
    for (int i = 0; i < 4; ++i) {
      int chunk = tid * 4 + i;
      int row = chunk >> 3, c = chunk & 7;
      size_t go = (size_t)(b0 + row) * 1024 + k0 + c * 8;
      bf16x8 vh = *(const bf16x8*)&X1hi[go];
      bf16x8 vl = *(const bf16x8*)&X1lo[go];
      int d = row * 64 + ((c ^ (row & 7)) << 3);
      *(bf16x8*)&lAhi[d] = vh;
      *(bf16x8*)&lAlo[d] = vl;
    }
    {
      const float* src = &W2[(size_t)(j0 + brow) * 1024 + k0 + bkq * 16];
      float4 f0 = *(const float4*)(src);
      float4 f1 = *(const float4*)(src + 4);
      float4 f2 = *(const float4*)(src + 8);
      float4 f3 = *(const float4*)(src + 12);
      float v[16] = {f0.x, f0.y, f0.z, f0.w, f1.x, f1.y, f1.z, f1.w,
                     f2.x, f2.y, f2.z, f2.w, f3.x, f3.y, f3.z, f3.w};
      bf16x8 h0, l0, h1, l1;
#pragma unroll
      for (int e = 0; e < 8; ++e) {
        ushort h = f2bf(v[e]);
        h0[e] = (short)h;
        l0[e] = (short)f2bf(v[e] - bf2f(h));
      }
#pragma unroll
      for (int e = 0; e < 8; ++e) {
        ushort h = f2bf(v[8 + e]);
        h1[e] = (short)h;
        l1[e] = (short)f2bf(v[8 + e] - bf2f(h));
      }
      int c0 = bkq * 2, c1 = bkq * 2 + 1;
      int d0 = brow * 64 + ((c0 ^ (brow & 7)) << 3);
      int d1 = brow * 64 + ((c1 ^ (brow & 7)) << 3);
      *(bf16x8*)&lBhi[d0] = h0;
      *(bf16x8*)&lBlo[d0] = l0;
      *(bf16x8*)&lBhi[d1] = h1;
      *(bf16x8*)&lBlo[d1] = l1;
    }
    __syncthreads();
#pragma unroll
    for (int kk = 0; kk < 2; ++kk) {
      bf16x8 ah[4], al[4], bh[2], bl[2];
#pragma unroll
      for (int mi = 0; mi < 4; ++mi) {
        int r = wm * 64 + mi * 16 + (lane & 15);
        int cc = (((kk << 2) + (lane >> 4)) ^ (r & 7)) << 3;
        ah[mi] = *(const bf16x8*)&lAhi[r * 64 + cc];
        al[mi] = *(const bf16x8*)&lAlo[r * 64 + cc];
      }
#pragma unroll
      for (int ni = 0; ni < 2; ++ni) {
        int r = wn * 32 + ni * 16 + (lane & 15);
        int cc = (((kk << 2) + (lane >> 4)) ^ (r & 7)) << 3;
        bh[ni] = *(const bf16x8*)&lBhi[r * 64 + cc];
        bl[ni] = *(const bf16x8*)&lBlo[r * 64 + cc];
      }
#pragma unroll
      for (int mi = 0; mi < 4; ++mi)
#pragma unroll
        for (int ni = 0; ni < 2; ++ni) {
          acc[mi][ni] = __builtin_amdgcn_mfma_f32_16x16x32_bf16(
              ah[mi], bh[ni], acc[mi][ni], 0, 0, 0);
          acc[mi][ni] = __builtin_amdgcn_mfma_f32_16x16x32_bf16(
              al[mi], bh[ni], acc[mi][ni], 0, 0, 0);
          acc[mi][ni] = __builtin_amdgcn_mfma_f32_16x16x32_bf16(
              ah[mi], bl[ni], acc[mi][ni], 0, 0, 0);
        }
    }
    __syncthreads();
  }
#pragma unroll
  for (int mi = 0; mi < 4; ++mi)
#pragma unroll
    for (int ni = 0; ni < 2; ++ni) {
      int col = j0 + wn * 32 + ni * 16 + (lane & 15);
#pragma unroll
      for (int r = 0; r < 4; ++r) {
        int row = b0 + wm * 64 + mi * 16 + (lane >> 4) * 4 + r;
        Y2[(size_t)row * 1024 + col] = acc[mi][ni][r];
      }
    }
#pragma unroll
  for (int ni = 0; ni < 2; ++ni) {
    float s = 0.f, q = 0.f;
#pragma unroll
    for (int mi = 0; mi < 4; ++mi)
#pragma unroll
      for (int r = 0; r < 4; ++r) {
        float v = acc[mi][ni][r];
        s += v;
        q += v * v;
      }
    s += __shfl_xor(s, 16);
    q += __shfl_xor(q, 16);
    s += __shfl_xor(s, 32);
    q += __shfl_xor(q, 32);
    if ((lane >> 4) == 0) {
      int col = j0 + wn * 32 + ni * 16 + lane;
      atomicAdd(&sA2[col], s);
      atomicAdd(&qA2[col], q);
    }
  }
}

// ---------------- k4: GEMM3 split-K, inline BN2+ReLU, atomic into Y3 ----------------
// tile 32(M) x 64(N), K-slice 256, grid (64,3,4). LDS transposed [k][row].
__global__ __launch_bounds__(256) void k4_gemm3(
    const float* __restrict__ Y2, const float* __restrict__ sA2,
    const float* __restrict__ qA2, const float* __restrict__ g2,
    const float* __restrict__ be2, const float* __restrict__ W3,
    float* __restrict__ Y3) {
  __shared__ float As[16][34], Bs[16][68];
  int b0 = blockIdx.x * 32, j0 = blockIdx.y * 64, kz = blockIdx.z;
  int tid = threadIdx.x;
  int tx = tid & 15, ty = tid >> 4;
  int arow = tid >> 3, akq = (tid & 7) * 2;
  int brow = tid >> 2, bkq = (tid & 3) * 4;
  int jb = j0 + brow;
  float c[2][4] = {};
  int kbase = kz * 256;
  for (int k0 = kbase; k0 < kbase + 256; k0 += 16) {
    float2 sv = *(const float2*)&sA2[k0 + akq];
    float2 qv = *(const float2*)&qA2[k0 + akq];
    float2 gv = *(const float2*)&g2[k0 + akq];
    float2 bev = *(const float2*)&be2[k0 + akq];
    float scx, shx, scy, shy;
    bn_coef(sv.x, qv.x, gv.x, bev.x, scx, shx);
    bn_coef(sv.y, qv.y, gv.y, bev.y, scy, shy);
    float2 av = *(const float2*)&Y2[(size_t)(b0 + arow) * 1024 + k0 + akq];
    As[akq + 0][arow] = fmaxf(0.f, av.x * scx + shx);
    As[akq + 1][arow] = fmaxf(0.f, av.y * scy + shy);
    float4 bv = make_float4(0.f, 0.f, 0.f, 0.f);
    if (jb < 150) bv = *(const float4*)&W3[(size_t)jb * 1024 + k0 + bkq];
    Bs[bkq + 0][brow] = bv.x;
    Bs[bkq + 1][brow] = bv.y;
    Bs[bkq + 2][brow] = bv.z;
    Bs[bkq + 3][brow] = bv.w;
    __syncthreads();
#pragma unroll
    for (int k = 0; k < 16; ++k) {
      float2 a = *(const float2*)&As[k][ty * 2];
      float4 b = *(const float4*)&Bs[k][tx * 4];
      c[0][0] += a.x * b.x; c[0][1] += a.x * b.y;
      c[0][2] += a.x * b.z; c[0][3] += a.x * b.w;
      c[1][0] += a.y * b.x; c[1][1] += a.y * b.y;
      c[1][2] += a.y * b.z; c[1][3] += a.y * b.w;
    }
    __syncthreads();
  }
#pragma unroll
  for (int i = 0; i < 2; ++i) {
    int r = b0 + ty * 2 + i;
#pragma unroll
    for (int jx = 0; jx < 4; ++jx) {
      int jj = j0 + tx * 4 + jx;
      if (jj < 150) atomicAdd(&Y3[(size_t)r * 150 + jj], c[i][jx]);
    }
  }
}

// ---------------- k5s: raw Y3 column stats -> atomic accumulators ----------------
__global__ __launch_bounds__(256) void k5s(const float* __restrict__ Y3,
                                           float* __restrict__ sA3,
                                           float* __restrict__ qA3) {
  int r0 = blockIdx.x * 8;
  int j = threadIdx.x;
  if (j >= 150) return;
  float s = 0.f, q = 0.f;
  for (int r = 0; r < 8; ++r) {
    float v = Y3[(size_t)(r0 + r) * 150 + j];
    s += v;
    q += v * v;
  }
  atomicAdd(&sA3[j], s);
  atomicAdd(&qA3[j], q);
}

// ---------------- k6a: inline BN3+ReLU + conv chain -> lorentz pre-struct ----------------
__global__ __launch_bounds__(256) void k6a(
    const float* __restrict__ Y3, const float* __restrict__ sA3,
    const float* __restrict__ qA3, const float* __restrict__ g3,
    const float* __restrict__ be3, const float* __restrict__ ct1_w,
    const float* __restrict__ ct1_b, const float* __restrict__ ct2_w,
    const float* __restrict__ ct2_b, const float* __restrict__ ct3_w,
    const float* __restrict__ ct3_b, const float* __restrict__ cf_w,
    const float* __restrict__ cf_b, float* __restrict__ Spre) {
  __shared__ float wt1[32], wb1[4], wt2[80], wb2[4], w3f[20];
  __shared__ float cfb2s;
  __shared__ float h0p[4][160];
  __shared__ float hA[4][4][308];
  __shared__ float hB[4][4][308];
  __shared__ float Srow[4][304];
  int tid = threadIdx.x;
  if (tid < 32) wt1[tid] = ct1_w[tid];
  else if (tid < 36) wb1[tid - 32] = ct1_b[tid - 32];
  else if (tid < 116) wt2[tid - 36] = ct2_w[tid - 36];
  else if (tid < 120) wb2[tid - 116] = ct2_b[tid - 116];
  else if (tid < 140) {
    int i = (tid - 120) / 5, j = (tid - 120) % 5;
    float s = 0.f;
#pragma unroll
    for (int p = 0; p < 4; ++p) s += cf_w[p] * ct3_w[(i * 4 + p) * 5 + j];
    w3f[tid - 120] = s;
  } else if (tid == 140) {
    float s = cf_b[0];
#pragma unroll
    for (int p = 0; p < 4; ++p) s += cf_w[p] * ct3_b[p];
    cfb2s = s;
  }
  int w = tid >> 6;
  int lane = tid & 63;
  int r = blockIdx.x * 4 + w;
  __syncthreads();
  for (int i = lane; i < 160; i += 64) {
    int k = i - 2;
    float v = 0.f;
    if (k >= 0 && k < 150) {
      float sc, sh;
      bn_coef(sA3[k], qA3[k], g3[k], be3[k], sc, sh);
      v = fmaxf(0.f, Y3[(size_t)r * 150 + k] * sc + sh);
    }
    h0p[w][i] = v;
  }
  if (lane < 8) {
    int z = (lane < 2) ? lane : (302 + lane - 2);
#pragma unroll
    for (int o = 0; o < 4; ++o) {
      hA[w][o][z] = 0.f;
      hB[w][o][z] = 0.f;
    }
  }
  __syncthreads();
  for (int t = lane; t < 300; t += 64) {
    int p1 = (t + 3) & 1;
    int base = (t + 3 - p1) >> 1;
    float x0 = h0p[w][2 + base];
    float x1 = h0p[w][1 + base];
    float x2 = h0p[w][base];
    float x3 = h0p[w][base - 1];
#pragma unroll
    for (int o = 0; o < 4; ++o) {
      float acc = wb1[o];
      acc += wt1[o * 8 + p1] * x0;
      acc += wt1[o * 8 + p1 + 2] * x1;
      acc += wt1[o * 8 + p1 + 4] * x2;
      acc += wt1[o * 8 + p1 + 6] * x3;
      hA[w][o][2 + t] = acc;
    }
  }
  __syncthreads();
  for (int t = lane; t < 300; t += 64) {
#pragma unroll
    for (int o = 0; o < 4; ++o) {
      float acc = wb2[o];
#pragma unroll
      for (int i = 0; i < 4; ++i)
#pragma unroll
        for (int j = 0; j < 5; ++j) acc += wt2[(i * 4 + o) * 5 + j] * hA[w][i][t + 4 - j];
      hB[w][o][2 + t] = acc;
    }
  }
  __syncthreads();
  for (int t = lane; t < 300; t += 64) {
    float acc = cfb2s;
#pragma unroll
    for (int i = 0; i < 4; ++i)
#pragma unroll
      for (int j = 0; j < 5; ++j) acc += w3f[i * 5 + j] * hB[w][i][t + 4 - j];
    Srow[w][t] = acc;
  }
  __syncthreads();
  for (int cc = lane; cc < 100; cc += 64) {
    float s0 = Srow[w][3 * cc], s1 = Srow[w][3 * cc + 1], s2 = Srow[w][3 * cc + 2];
    float4 p;
    p.x = s0 * s0;
    p.y = s1 * s1;
    p.z = s2 * s2;
    p.w = 0.f;
    *(float4*)&Spre[((size_t)r * 100 + cc) * 4] = p;
  }
}

// ---------------- k6b: lorentz, cc-split x4, wave-uniform scalar loads ----------------
__global__ __launch_bounds__(320) void k6b(const float* __restrict__ Spre,
                                           float* __restrict__ out) {
  int b = blockIdx.x;
  int l = threadIdx.x;
  float wl = 0.8f + (float)l * (1.0f / 300.0f);
  float w2l = wl * wl;
  float acc = 0.f;
  const float4* pp = (const float4*)&Spre[(size_t)b * 400] + blockIdx.y * 25;
#pragma unroll 5
  for (int cc = 0; cc < 25; ++cc) {
    float4 p = pp[cc];
    float wp2 = p.x, s1sq = p.y, s2sq = p.z;
    float sub1 = s1sq - w2l;
    float denom = fmaf(sub1, sub1, w2l * s2sq);
    float inv = __builtin_amdgcn_rcpf(denom);
    float u = wp2 * inv;
    float tp = u * (wp2 + sub1);
    float tm = u * (wp2 - sub1);
    float n = 0.70710678f * __builtin_amdgcn_sqrtf(fmaxf(tp, 0.f));
    float np1 = n + 1.0f;
    float den2 = fmaf(np1, np1, 0.5f * fmaxf(tm, 0.f));
    acc = fmaf(4.0f * n, __builtin_amdgcn_rcpf(den2), acc);
  }
  if (l < 300) atomicAdd(&out[(size_t)b * 300 + l], acc);
}

extern "C" void kernel_launch(void* const* d_in, const int* in_sizes, int n_in,
                              void* d_out, int out_size, void* d_ws,
                              size_t ws_size, hipStream_t stream) {
  const float* G = (const float*)d_in[0];
  const float* w1 = (const float*)d_in[1];
  const float* g1 = (const float*)d_in[3];
  const float* be1 = (const float*)d_in[4];
  const float* w2 = (const float*)d_in[5];
  const float* g2 = (const float*)d_in[7];
  const float* be2 = (const float*)d_in[8];
  const float* w3 = (const float*)d_in[9];
  const float* g3 = (const float*)d_in[11];
  const float* be3 = (const float*)d_in[12];
  const float* ct1_w = (const float*)d_in[13];
  const float* ct1_b = (const float*)d_in[14];
  const float* ct2_w = (const float*)d_in[15];
  const float* ct2_b = (const float*)d_in[16];
  const float* ct3_w = (const float*)d_in[17];
  const float* ct3_b = (const float*)d_in[18];
  const float* cf_w = (const float*)d_in[19];
  const float* cf_b = (const float*)d_in[20];
  float* out = (float*)d_out;

  float* ws = (float*)d_ws;
  // [0, 2097152): Y2 (k2->k4)
  float* Y2 = ws;
  // [2097152, 3145728): X1hi (k1c->k2) | Spre (k6a->k6b, after k4)
  ushort* X1hi = (ushort*)(ws + 2097152);
  float* Spre = ws + 2097152;
  // [3145728, 4194304): X1lo (k1c->k2) | Y3 @ tail (zeroed+written after k2)
  ushort* X1lo = (ushort*)(ws + 3145728);
  float* Y3 = ws + 3887104;  // 307200 floats
  // [4194304, ...): atomic stat accumulators (zeroed up front)
  float* sA1 = ws + 4194304;
  float* qA1 = sA1 + 1024;
  float* sA2 = sA1 + 2048;
  float* qA2 = sA1 + 3072;
  float* sA3 = sA1 + 4096;
  float* qA3 = sA1 + 4288;  // 160 pad each

  hipMemsetAsync(sA1, 0, 4448 * sizeof(float), stream);
  hipMemsetAsync(out, 0, (size_t)out_size * sizeof(float), stream);

  k1s<<<256, 256, 0, stream>>>(G, w1, sA1, qA1);
  k1c<<<256, 256, 0, stream>>>(G, w1, sA1, qA1, g1, be1, X1hi, X1lo);
  k2_mfma<<<256, 256, 0, stream>>>(X1hi, X1lo, w2, Y2, sA2, qA2);
  hipMemsetAsync(Y3, 0, 307200 * sizeof(float), stream);
  k4_gemm3<<<dim3(64, 3, 4), 256, 0, stream>>>(Y2, sA2, qA2, g2, be2, w3, Y3);
  k5s<<<256, 256, 0, stream>>>(Y3, sA3, qA3);
  k6a<<<512, 256, 0, stream>>>(Y3, sA3, qA3, g3, be3, ct1_w, ct1_b, ct2_w,
                               ct2_b, ct3_w, ct3_b, cf_w, cf_b, Spre);
  k6b<<<dim3(2048, 4), 320, 0, stream>>>(Spre, out);
}

// Round 7
// 166.148 us; speedup vs baseline: 1.7153x; 1.0422x over previous
//
#include <hip/hip_runtime.h>
#include <hip/hip_bf16.h>

#define EPS 1e-5f

typedef __attribute__((ext_vector_type(8))) short bf16x8;
typedef __attribute__((ext_vector_type(4))) float f32x4;

__device__ __forceinline__ ushort f2bf(float x) {
  __hip_bfloat16 h = __float2bfloat16(x);
  return *reinterpret_cast<ushort*>(&h);
}
__device__ __forceinline__ float bf2f(ushort u) {
  __hip_bfloat16 h;
  *reinterpret_cast<ushort*>(&h) = u;
  return __bfloat162float(h);
}
__device__ __forceinline__ void bn_coef(float s, float q, float g, float be,
                                        float& sc, float& sh) {
  float mu = s * (1.f / 2048.f);
  float var = q * (1.f / 2048.f) - mu * mu;
  sc = g * rsqrtf(var + EPS);
  sh = be - mu * sc;
}

// ---------------- k1s: layer1 raw stats -> atomic accumulators ----------------
__global__ __launch_bounds__(256) void k1s(const float* __restrict__ G,
                                           const float* __restrict__ W1,
                                           float* __restrict__ sA1,
                                           float* __restrict__ qA1) {
  int r0 = blockIdx.x * 8;
  int c = threadIdx.x * 4;
  float w[4][8];
#pragma unroll
  for (int q = 0; q < 4; ++q)
#pragma unroll
    for (int k = 0; k < 8; ++k) w[q][k] = W1[(c + q) * 8 + k];
  float s[4] = {}, ss[4] = {};
  for (int r = 0; r < 8; ++r) {
    const float4 g0 = *(const float4*)&G[(size_t)(r0 + r) * 8];
    const float4 g1 = *(const float4*)&G[(size_t)(r0 + r) * 8 + 4];
    float gr[8] = {g0.x, g0.y, g0.z, g0.w, g1.x, g1.y, g1.z, g1.w};
#pragma unroll
    for (int q = 0; q < 4; ++q) {
      float acc = 0.f;
#pragma unroll
      for (int k = 0; k < 8; ++k) acc += gr[k] * w[q][k];
      s[q] += acc;
      ss[q] += acc * acc;
    }
  }
#pragma unroll
  for (int q = 0; q < 4; ++q) {
    atomicAdd(&sA1[c + q], s[q]);
    atomicAdd(&qA1[c + q], ss[q]);
  }
}

// ---------------- k1c: recompute raw Y1, inline BN1+ReLU, split bf16 hi/lo ----------------
__global__ __launch_bounds__(256) void k1c(
    const float* __restrict__ G, const float* __restrict__ W1,
    const float* __restrict__ sA1, const float* __restrict__ qA1,
    const float* __restrict__ g1, const float* __restrict__ be1,
    ushort* __restrict__ X1hi, ushort* __restrict__ X1lo) {
  int r0 = blockIdx.x * 8;
  int c = threadIdx.x * 4;
  float w[4][8];
#pragma unroll
  for (int q = 0; q < 4; ++q)
#pragma unroll
    for (int k = 0; k < 8; ++k) w[q][k] = W1[(c + q) * 8 + k];
  float sc[4], sh[4];
#pragma unroll
  for (int q = 0; q < 4; ++q)
    bn_coef(sA1[c + q], qA1[c + q], g1[c + q], be1[c + q], sc[q], sh[q]);
  for (int r = 0; r < 8; ++r) {
    const float4 g0 = *(const float4*)&G[(size_t)(r0 + r) * 8];
    const float4 g1v = *(const float4*)&G[(size_t)(r0 + r) * 8 + 4];
    float gr[8] = {g0.x, g0.y, g0.z, g0.w, g1v.x, g1v.y, g1v.z, g1v.w};
    ushort hs[4], ls[4];
#pragma unroll
    for (int q = 0; q < 4; ++q) {
      float acc = 0.f;
#pragma unroll
      for (int k = 0; k < 8; ++k) acc += gr[k] * w[q][k];
      float x = fmaxf(0.f, acc * sc[q] + sh[q]);
      ushort h = f2bf(x);
      float hf = bf2f(h);
      hs[q] = h;
      ls[q] = f2bf(x - hf);
    }
    size_t o = (size_t)(r0 + r) * 1024 + c;
    *(ushort4*)&X1hi[o] = make_ushort4(hs[0], hs[1], hs[2], hs[3]);
    *(ushort4*)&X1lo[o] = make_ushort4(ls[0], ls[1], ls[2], ls[3]);
  }
}

// ---------------- k2: MFMA bf16 hi/lo GEMM2 + fused column-stat atomics ----------------
__global__ __launch_bounds__(256) void k2_mfma(
    const ushort* __restrict__ X1hi, const ushort* __restrict__ X1lo,
    const float* __restrict__ W2, float* __restrict__ Y2,
    float* __restrict__ sA2, float* __restrict__ qA2) {
  __shared__ short lAhi[128 * 64], lAlo[128 * 64];
  __shared__ short lBhi[64 * 64], lBlo[64 * 64];
  int id = blockIdx.x;
  int xcd = id & 7, slot = id >> 3;
  int g = slot >> 4, wi = slot & 15;
  int bx = (xcd & 3) * 4 + (wi & 3);
  int by = ((xcd >> 2) * 2 + g) * 4 + (wi >> 2);
  int b0 = bx * 128, j0 = by * 64;
  int tid = threadIdx.x;
  int lane = tid & 63, wave = tid >> 6;
  int wm = wave >> 1, wn = wave & 1;
  int brow = tid >> 2, bkq = tid & 3;
  f32x4 acc[4][2] = {};
  for (int k0 = 0; k0 < 1024; k0 += 64) {
#pragma unroll
    for (int i = 0; i < 4; ++i) {
      int chunk = tid * 4 + i;
      int row = chunk >> 3, c = chunk & 7;
      size_t go = (size_t)(b0 + row) * 1024 + k0 + c * 8;
      bf16x8 vh = *(const bf16x8*)&X1hi[go];
      bf16x8 vl = *(const bf16x8*)&X1lo[go];
      int d = row * 64 + ((c ^ (row & 7)) << 3);
      *(bf16x8*)&lAhi[d] = vh;
      *(bf16x8*)&lAlo[d] = vl;
    }
    {
      const float* src = &W2[(size_t)(j0 + brow) * 1024 + k0 + bkq * 16];
      float4 f0 = *(const float4*)(src);
      float4 f1 = *(const float4*)(src + 4);
      float4 f2 = *(const float4*)(src + 8);
      float4 f3 = *(const float4*)(src + 12);
      float v[16] = {f0.x, f0.y, f0.z, f0.w, f1.x, f1.y, f1.z, f1.w,
                     f2.x, f2.y, f2.z, f2.w, f3.x, f3.y, f3.z, f3.w};
      bf16x8 h0, l0, h1, l1;
#pragma unroll
      for (int e = 0; e < 8; ++e) {
        ushort h = f2bf(v[e]);
        h0[e] = (short)h;
        l0[e] = (short)f2bf(v[e] - bf2f(h));
      }
#pragma unroll
      for (int e = 0; e < 8; ++e) {
        ushort h = f2bf(v[8 + e]);
        h1[e] = (short)h;
        l1[e] = (short)f2bf(v[8 + e] - bf2f(h));
      }
      int c0 = bkq * 2, c1 = bkq * 2 + 1;
      int d0 = brow * 64 + ((c0 ^ (brow & 7)) << 3);
      int d1 = brow * 64 + ((c1 ^ (brow & 7)) << 3);
      *(bf16x8*)&lBhi[d0] = h0;
      *(bf16x8*)&lBlo[d0] = l0;
      *(bf16x8*)&lBhi[d1] = h1;
      *(bf16x8*)&lBlo[d1] = l1;
    }
    __syncthreads();
#pragma unroll
    for (int kk = 0; kk < 2; ++kk) {
      bf16x8 ah[4], al[4], bh[2], bl[2];
#pragma unroll
      for (int mi = 0; mi < 4; ++mi) {
        int r = wm * 64 + mi * 16 + (lane & 15);
        int cc = (((kk << 2) + (lane >> 4)) ^ (r & 7)) << 3;
        ah[mi] = *(const bf16x8*)&lAhi[r * 64 + cc];
        al[mi] = *(const bf16x8*)&lAlo[r * 64 + cc];
      }
#pragma unroll
      for (int ni = 0; ni < 2; ++ni) {
        int r = wn * 32 + ni * 16 + (lane & 15);
        int cc = (((kk << 2) + (lane >> 4)) ^ (r & 7)) << 3;
        bh[ni] = *(const bf16x8*)&lBhi[r * 64 + cc];
        bl[ni] = *(const bf16x8*)&lBlo[r * 64 + cc];
      }
#pragma unroll
      for (int mi = 0; mi < 4; ++mi)
#pragma unroll
        for (int ni = 0; ni < 2; ++ni) {
          acc[mi][ni] = __builtin_amdgcn_mfma_f32_16x16x32_bf16(
              ah[mi], bh[ni], acc[mi][ni], 0, 0, 0);
          acc[mi][ni] = __builtin_amdgcn_mfma_f32_16x16x32_bf16(
              al[mi], bh[ni], acc[mi][ni], 0, 0, 0);
          acc[mi][ni] = __builtin_amdgcn_mfma_f32_16x16x32_bf16(
              ah[mi], bl[ni], acc[mi][ni], 0, 0, 0);
        }
    }
    __syncthreads();
  }
#pragma unroll
  for (int mi = 0; mi < 4; ++mi)
#pragma unroll
    for (int ni = 0; ni < 2; ++ni) {
      int col = j0 + wn * 32 + ni * 16 + (lane & 15);
#pragma unroll
      for (int r = 0; r < 4; ++r) {
        int row = b0 + wm * 64 + mi * 16 + (lane >> 4) * 4 + r;
        Y2[(size_t)row * 1024 + col] = acc[mi][ni][r];
      }
    }
#pragma unroll
  for (int ni = 0; ni < 2; ++ni) {
    float s = 0.f, q = 0.f;
#pragma unroll
    for (int mi = 0; mi < 4; ++mi)
#pragma unroll
      for (int r = 0; r < 4; ++r) {
        float v = acc[mi][ni][r];
        s += v;
        q += v * v;
      }
    s += __shfl_xor(s, 16);
    q += __shfl_xor(q, 16);
    s += __shfl_xor(s, 32);
    q += __shfl_xor(q, 32);
    if ((lane >> 4) == 0) {
      int col = j0 + wn * 32 + ni * 16 + lane;
      atomicAdd(&sA2[col], s);
      atomicAdd(&qA2[col], q);
    }
  }
}

// ---------------- k4w: W3 -> bf16 hi/lo [n][k] (n padded to 160) + BN2 coefs ----------------
__global__ __launch_bounds__(256) void k4w(
    const float* __restrict__ W3, const float* __restrict__ sA2,
    const float* __restrict__ qA2, const float* __restrict__ g2,
    const float* __restrict__ be2, ushort* __restrict__ W3hi,
    ushort* __restrict__ W3lo, float* __restrict__ scale2,
    float* __restrict__ shift2) {
  int n = blockIdx.x;
  int tid = threadIdx.x;
  if (n < 160) {
    int c = tid * 4;
    float4 v = make_float4(0.f, 0.f, 0.f, 0.f);
    if (n < 150) v = *(const float4*)&W3[(size_t)n * 1024 + c];
    float e[4] = {v.x, v.y, v.z, v.w};
    ushort hh[4], ll[4];
#pragma unroll
    for (int q = 0; q < 4; ++q) {
      hh[q] = f2bf(e[q]);
      ll[q] = f2bf(e[q] - bf2f(hh[q]));
    }
    *(ushort4*)&W3hi[(size_t)n * 1024 + c] = make_ushort4(hh[0], hh[1], hh[2], hh[3]);
    *(ushort4*)&W3lo[(size_t)n * 1024 + c] = make_ushort4(ll[0], ll[1], ll[2], ll[3]);
  } else {
    int j = tid * 4;
#pragma unroll
    for (int q = 0; q < 4; ++q) {
      float sc, sh;
      bn_coef(sA2[j + q], qA2[j + q], g2[j + q], be2[j + q], sc, sh);
      scale2[j + q] = sc;
      shift2[j + q] = sh;
    }
  }
}

// ---------------- k4: MFMA GEMM3, inline BN2+ReLU on A, atomic into Y3 ----------------
// grid (64, 8): M-tile 32, N=160 (padded), K-slice 128. B-frags direct from global.
__global__ __launch_bounds__(256) void k4_mfma(
    const float* __restrict__ Y2, const float* __restrict__ scale2,
    const float* __restrict__ shift2, const ushort* __restrict__ W3hi,
    const ushort* __restrict__ W3lo, float* __restrict__ Y3) {
  __shared__ short lAhi[32 * 64], lAlo[32 * 64];
  int b0 = blockIdx.x * 32;
  int kb = blockIdx.y * 128;
  int tid = threadIdx.x;
  int lane = tid & 63, wave = tid >> 6;
  int wm = wave & 1, wn = wave >> 1;  // M half (16 rows), N half (80 cols)
  f32x4 acc[5] = {};
  int srow = tid >> 3, sch = tid & 7;  // staging: 32 rows x 8 chunks of 8
  for (int k0 = 0; k0 < 128; k0 += 64) {
    int kg = kb + k0 + sch * 8;
    const float* src = &Y2[(size_t)(b0 + srow) * 1024 + kg];
    float4 f0 = *(const float4*)src;
    float4 f1 = *(const float4*)(src + 4);
    float4 c0 = *(const float4*)&scale2[kg];
    float4 c1 = *(const float4*)&scale2[kg + 4];
    float4 s0 = *(const float4*)&shift2[kg];
    float4 s1 = *(const float4*)&shift2[kg + 4];
    float e[8] = {f0.x, f0.y, f0.z, f0.w, f1.x, f1.y, f1.z, f1.w};
    float cs[8] = {c0.x, c0.y, c0.z, c0.w, c1.x, c1.y, c1.z, c1.w};
    float sh[8] = {s0.x, s0.y, s0.z, s0.w, s1.x, s1.y, s1.z, s1.w};
    bf16x8 hh, ll;
#pragma unroll
    for (int q = 0; q < 8; ++q) {
      float x = fmaxf(0.f, fmaf(e[q], cs[q], sh[q]));
      ushort h = f2bf(x);
      hh[q] = (short)h;
      ll[q] = (short)f2bf(x - bf2f(h));
    }
    if (k0) __syncthreads();
    int d = srow * 64 + ((sch ^ (srow & 7)) << 3);
    *(bf16x8*)&lAhi[d] = hh;
    *(bf16x8*)&lAlo[d] = ll;
    __syncthreads();
#pragma unroll
    for (int kk = 0; kk < 2; ++kk) {
      int r = wm * 16 + (lane & 15);
      int ch = kk * 4 + (lane >> 4);
      int ad = r * 64 + ((ch ^ (r & 7)) << 3);
      bf16x8 ah = *(const bf16x8*)&lAhi[ad];
      bf16x8 al = *(const bf16x8*)&lAlo[ad];
#pragma unroll
      for (int ni = 0; ni < 5; ++ni) {
        int col = wn * 80 + ni * 16 + (lane & 15);
        size_t wo = (size_t)col * 1024 + kb + k0 + kk * 32 + (lane >> 4) * 8;
        bf16x8 bh = *(const bf16x8*)&W3hi[wo];
        bf16x8 bl = *(const bf16x8*)&W3lo[wo];
        acc[ni] = __builtin_amdgcn_mfma_f32_16x16x32_bf16(ah, bh, acc[ni], 0, 0, 0);
        acc[ni] = __builtin_amdgcn_mfma_f32_16x16x32_bf16(al, bh, acc[ni], 0, 0, 0);
        acc[ni] = __builtin_amdgcn_mfma_f32_16x16x32_bf16(ah, bl, acc[ni], 0, 0, 0);
      }
    }
  }
#pragma unroll
  for (int ni = 0; ni < 5; ++ni) {
    int col = wn * 80 + ni * 16 + (lane & 15);
    if (col < 150) {
#pragma unroll
      for (int r = 0; r < 4; ++r) {
        int row = b0 + wm * 16 + (lane >> 4) * 4 + r;
        atomicAdd(&Y3[(size_t)row * 150 + col], acc[ni][r]);
      }
    }
  }
}

// ---------------- k5s: raw Y3 column stats -> atomic accumulators ----------------
__global__ __launch_bounds__(256) void k5s(const float* __restrict__ Y3,
                                           float* __restrict__ sA3,
                                           float* __restrict__ qA3) {
  int r0 = blockIdx.x * 8;
  int j = threadIdx.x;
  if (j >= 150) return;
  float s = 0.f, q = 0.f;
  for (int r = 0; r < 8; ++r) {
    float v = Y3[(size_t)(r0 + r) * 150 + j];
    s += v;
    q += v * v;
  }
  atomicAdd(&sA3[j], s);
  atomicAdd(&qA3[j], q);
}

// ---------------- k6a: inline BN3+ReLU + conv chain -> lorentz pre-struct ----------------
__global__ __launch_bounds__(256) void k6a(
    const float* __restrict__ Y3, const float* __restrict__ sA3,
    const float* __restrict__ qA3, const float* __restrict__ g3,
    const float* __restrict__ be3, const float* __restrict__ ct1_w,
    const float* __restrict__ ct1_b, const float* __restrict__ ct2_w,
    const float* __restrict__ ct2_b, const float* __restrict__ ct3_w,
    const float* __restrict__ ct3_b, const float* __restrict__ cf_w,
    const float* __restrict__ cf_b, float* __restrict__ Spre) {
  __shared__ float wt1[32], wb1[4], wt2[80], wb2[4], w3f[20];
  __shared__ float cfb2s;
  __shared__ float h0p[4][160];
  __shared__ float hA[4][4][308];
  __shared__ float hB[4][4][308];
  __shared__ float Srow[4][304];
  int tid = threadIdx.x;
  if (tid < 32) wt1[tid] = ct1_w[tid];
  else if (tid < 36) wb1[tid - 32] = ct1_b[tid - 32];
  else if (tid < 116) wt2[tid - 36] = ct2_w[tid - 36];
  else if (tid < 120) wb2[tid - 116] = ct2_b[tid - 116];
  else if (tid < 140) {
    int i = (tid - 120) / 5, j = (tid - 120) % 5;
    float s = 0.f;
#pragma unroll
    for (int p = 0; p < 4; ++p) s += cf_w[p] * ct3_w[(i * 4 + p) * 5 + j];
    w3f[tid - 120] = s;
  } else if (tid == 140) {
    float s = cf_b[0];
#pragma unroll
    for (int p = 0; p < 4; ++p) s += cf_w[p] * ct3_b[p];
    cfb2s = s;
  }
  int w = tid >> 6;
  int lane = tid & 63;
  int r = blockIdx.x * 4 + w;
  __syncthreads();
  for (int i = lane; i < 160; i += 64) {
    int k = i - 2;
    float v = 0.f;
    if (k >= 0 && k < 150) {
      float sc, sh;
      bn_coef(sA3[k], qA3[k], g3[k], be3[k], sc, sh);
      v = fmaxf(0.f, Y3[(size_t)r * 150 + k] * sc + sh);
    }
    h0p[w][i] = v;
  }
  if (lane < 8) {
    int z = (lane < 2) ? lane : (302 + lane - 2);
#pragma unroll
    for (int o = 0; o < 4; ++o) {
      hA[w][o][z] = 0.f;
      hB[w][o][z] = 0.f;
    }
  }
  __syncthreads();
  for (int t = lane; t < 300; t += 64) {
    int p1 = (t + 3) & 1;
    int base = (t + 3 - p1) >> 1;
    float x0 = h0p[w][2 + base];
    float x1 = h0p[w][1 + base];
    float x2 = h0p[w][base];
    float x3 = h0p[w][base - 1];
#pragma unroll
    for (int o = 0; o < 4; ++o) {
      float acc = wb1[o];
      acc += wt1[o * 8 + p1] * x0;
      acc += wt1[o * 8 + p1 + 2] * x1;
      acc += wt1[o * 8 + p1 + 4] * x2;
      acc += wt1[o * 8 + p1 + 6] * x3;
      hA[w][o][2 + t] = acc;
    }
  }
  __syncthreads();
  for (int t = lane; t < 300; t += 64) {
#pragma unroll
    for (int o = 0; o < 4; ++o) {
      float acc = wb2[o];
#pragma unroll
      for (int i = 0; i < 4; ++i)
#pragma unroll
        for (int j = 0; j < 5; ++j) acc += wt2[(i * 4 + o) * 5 + j] * hA[w][i][t + 4 - j];
      hB[w][o][2 + t] = acc;
    }
  }
  __syncthreads();
  for (int t = lane; t < 300; t += 64) {
    float acc = cfb2s;
#pragma unroll
    for (int i = 0; i < 4; ++i)
#pragma unroll
      for (int j = 0; j < 5; ++j) acc += w3f[i * 5 + j] * hB[w][i][t + 4 - j];
    Srow[w][t] = acc;
  }
  __syncthreads();
  for (int cc = lane; cc < 100; cc += 64) {
    float s0 = Srow[w][3 * cc], s1 = Srow[w][3 * cc + 1], s2 = Srow[w][3 * cc + 2];
    float4 p;
    p.x = s0 * s0;
    p.y = s1 * s1;
    p.z = s2 * s2;
    p.w = 0.f;
    *(float4*)&Spre[((size_t)r * 100 + cc) * 4] = p;
  }
}

// ---------------- k6b: lorentz, cc-split x8, wave-uniform scalar loads ----------------
__global__ __launch_bounds__(320) void k6b(const float* __restrict__ Spre,
                                           float* __restrict__ out) {
  int b = blockIdx.x;
  int y = blockIdx.y;
  int l = threadIdx.x;
  int start = y * 12 + min(y, 4);
  int count = 12 + (y < 4 ? 1 : 0);
  float wl = 0.8f + (float)l * (1.0f / 300.0f);
  float w2l = wl * wl;
  float acc = 0.f;
  const float4* pp = (const float4*)&Spre[(size_t)b * 400] + start;
  for (int cc = 0; cc < count; ++cc) {
    float4 p = pp[cc];
    float wp2 = p.x, s1sq = p.y, s2sq = p.z;
    float sub1 = s1sq - w2l;
    float denom = fmaf(sub1, sub1, w2l * s2sq);
    float inv = __builtin_amdgcn_rcpf(denom);
    float u = wp2 * inv;
    float tp = u * (wp2 + sub1);
    float tm = u * (wp2 - sub1);
    float n = 0.70710678f * __builtin_amdgcn_sqrtf(fmaxf(tp, 0.f));
    float np1 = n + 1.0f;
    float den2 = fmaf(np1, np1, 0.5f * fmaxf(tm, 0.f));
    acc = fmaf(4.0f * n, __builtin_amdgcn_rcpf(den2), acc);
  }
  if (l < 300) atomicAdd(&out[(size_t)b * 300 + l], acc);
}

extern "C" void kernel_launch(void* const* d_in, const int* in_sizes, int n_in,
                              void* d_out, int out_size, void* d_ws,
                              size_t ws_size, hipStream_t stream) {
  const float* G = (const float*)d_in[0];
  const float* w1 = (const float*)d_in[1];
  const float* g1 = (const float*)d_in[3];
  const float* be1 = (const float*)d_in[4];
  const float* w2 = (const float*)d_in[5];
  const float* g2 = (const float*)d_in[7];
  const float* be2 = (const float*)d_in[8];
  const float* w3 = (const float*)d_in[9];
  const float* g3 = (const float*)d_in[11];
  const float* be3 = (const float*)d_in[12];
  const float* ct1_w = (const float*)d_in[13];
  const float* ct1_b = (const float*)d_in[14];
  const float* ct2_w = (const float*)d_in[15];
  const float* ct2_b = (const float*)d_in[16];
  const float* ct3_w = (const float*)d_in[17];
  const float* ct3_b = (const float*)d_in[18];
  const float* cf_w = (const float*)d_in[19];
  const float* cf_b = (const float*)d_in[20];
  float* out = (float*)d_out;

  float* ws = (float*)d_ws;
  // [0, 2097152): Y2 (k2->k4)
  float* Y2 = ws;
  // [2097152, 3145728): X1hi (k1c->k2) | then W3hi/W3lo/scale2/shift2 (k4w->k4)
  //                     | then Spre (k6a->k6b)
  ushort* X1hi = (ushort*)(ws + 2097152);
  ushort* W3hi = (ushort*)(ws + 2097152);   // 163840 ushorts = 81920 floats
  ushort* W3lo = (ushort*)(ws + 2179072);   // 163840 ushorts
  float* scale2 = ws + 2260992;             // 1024
  float* shift2 = ws + 2262016;             // 1024
  float* Spre = ws + 2097152;               // 819200 floats (after k4)
  // [3145728, 4194304): X1lo (k1c->k2) | Y3 @ tail (zeroed+written after k2)
  ushort* X1lo = (ushort*)(ws + 3145728);
  float* Y3 = ws + 3887104;  // 307200 floats
  // [4194304, ...): atomic stat accumulators (zeroed up front)
  float* sA1 = ws + 4194304;
  float* qA1 = sA1 + 1024;
  float* sA2 = sA1 + 2048;
  float* qA2 = sA1 + 3072;
  float* sA3 = sA1 + 4096;
  float* qA3 = sA1 + 4288;

  hipMemsetAsync(sA1, 0, 4448 * sizeof(float), stream);
  hipMemsetAsync(out, 0, (size_t)out_size * sizeof(float), stream);

  k1s<<<256, 256, 0, stream>>>(G, w1, sA1, qA1);
  k1c<<<256, 256, 0, stream>>>(G, w1, sA1, qA1, g1, be1, X1hi, X1lo);
  k2_mfma<<<256, 256, 0, stream>>>(X1hi, X1lo, w2, Y2, sA2, qA2);
  hipMemsetAsync(Y3, 0, 307200 * sizeof(float), stream);
  k4w<<<161, 256, 0, stream>>>(w3, sA2, qA2, g2, be2, W3hi, W3lo, scale2, shift2);
  k4_mfma<<<dim3(64, 8), 256, 0, stream>>>(Y2, scale2, shift2, W3hi, W3lo, Y3);
  k5s<<<256, 256, 0, stream>>>(Y3, sA3, qA3);
  k6a<<<512, 256, 0, stream>>>(Y3, sA3, qA3, g3, be3, ct1_w, ct1_b, ct2_w,
                               ct2_b, ct3_w, ct3_b, cf_w, cf_b, Spre);
  k6b<<<dim3(2048, 8), 320, 0, stream>>>(Spre, out);
}

// Round 8
// 161.115 us; speedup vs baseline: 1.7689x; 1.0312x over previous
//
#include <hip/hip_runtime.h>
#include <hip/hip_bf16.h>

#define EPS 1e-5f

typedef __attribute__((ext_vector_type(8))) short bf16x8;
typedef __attribute__((ext_vector_type(4))) float f32x4;

// truncation-based hi/lo bf16 split: hi = trunc16(x), lo = trunc16(x - hi)
__device__ __forceinline__ void split2(float x, short& h, short& l) {
  unsigned u = __float_as_uint(x);
  h = (short)(u >> 16);
  float hf = __uint_as_float(u & 0xFFFF0000u);
  l = (short)(__float_as_uint(x - hf) >> 16);
}
__device__ __forceinline__ void bn_coef(float s, float q, float g, float be,
                                        float& sc, float& sh) {
  float mu = s * (1.f / 2048.f);
  float var = q * (1.f / 2048.f) - mu * mu;
  sc = g * rsqrtf(var + EPS);
  sh = be - mu * sc;
}

// ---------------- k1s: layer1 raw stats -> atomic accumulators ----------------
__global__ __launch_bounds__(256) void k1s(const float* __restrict__ G,
                                           const float* __restrict__ W1,
                                           float* __restrict__ sA1,
                                           float* __restrict__ qA1) {
  int r0 = blockIdx.x * 8;
  int c = threadIdx.x * 4;
  float w[4][8];
#pragma unroll
  for (int q = 0; q < 4; ++q)
#pragma unroll
    for (int k = 0; k < 8; ++k) w[q][k] = W1[(c + q) * 8 + k];
  float s[4] = {}, ss[4] = {};
  for (int r = 0; r < 8; ++r) {
    const float4 g0 = *(const float4*)&G[(size_t)(r0 + r) * 8];
    const float4 g1 = *(const float4*)&G[(size_t)(r0 + r) * 8 + 4];
    float gr[8] = {g0.x, g0.y, g0.z, g0.w, g1.x, g1.y, g1.z, g1.w};
#pragma unroll
    for (int q = 0; q < 4; ++q) {
      float acc = 0.f;
#pragma unroll
      for (int k = 0; k < 8; ++k) acc += gr[k] * w[q][k];
      s[q] += acc;
      ss[q] += acc * acc;
    }
  }
#pragma unroll
  for (int q = 0; q < 4; ++q) {
    atomicAdd(&sA1[c + q], s[q]);
    atomicAdd(&qA1[c + q], ss[q]);
  }
}

// ---------------- k1c: recompute raw Y1, inline BN1+ReLU, split bf16 hi/lo ----------------
__global__ __launch_bounds__(256) void k1c(
    const float* __restrict__ G, const float* __restrict__ W1,
    const float* __restrict__ sA1, const float* __restrict__ qA1,
    const float* __restrict__ g1, const float* __restrict__ be1,
    ushort* __restrict__ X1hi, ushort* __restrict__ X1lo) {
  int r0 = blockIdx.x * 8;
  int c = threadIdx.x * 4;
  float w[4][8];
#pragma unroll
  for (int q = 0; q < 4; ++q)
#pragma unroll
    for (int k = 0; k < 8; ++k) w[q][k] = W1[(c + q) * 8 + k];
  float sc[4], sh[4];
#pragma unroll
  for (int q = 0; q < 4; ++q)
    bn_coef(sA1[c + q], qA1[c + q], g1[c + q], be1[c + q], sc[q], sh[q]);
  for (int r = 0; r < 8; ++r) {
    const float4 g0 = *(const float4*)&G[(size_t)(r0 + r) * 8];
    const float4 g1v = *(const float4*)&G[(size_t)(r0 + r) * 8 + 4];
    float gr[8] = {g0.x, g0.y, g0.z, g0.w, g1v.x, g1v.y, g1v.z, g1v.w};
    short hs[4], ls[4];
#pragma unroll
    for (int q = 0; q < 4; ++q) {
      float acc = 0.f;
#pragma unroll
      for (int k = 0; k < 8; ++k) acc += gr[k] * w[q][k];
      float x = fmaxf(0.f, acc * sc[q] + sh[q]);
      split2(x, hs[q], ls[q]);
    }
    size_t o = (size_t)(r0 + r) * 1024 + c;
    *(ushort4*)&X1hi[o] = make_ushort4((ushort)hs[0], (ushort)hs[1],
                                       (ushort)hs[2], (ushort)hs[3]);
    *(ushort4*)&X1lo[o] = make_ushort4((ushort)ls[0], (ushort)ls[1],
                                       (ushort)ls[2], (ushort)ls[3]);
  }
}

// ---------------- k2: MFMA bf16 hi/lo GEMM2, 8 waves, fused stats ----------------
__global__ __launch_bounds__(512) void k2_mfma(
    const ushort* __restrict__ X1hi, const ushort* __restrict__ X1lo,
    const float* __restrict__ W2, float* __restrict__ Y2,
    float* __restrict__ sA2, float* __restrict__ qA2) {
  __shared__ short lAhi[128 * 64], lAlo[128 * 64];
  __shared__ short lBhi[64 * 64], lBlo[64 * 64];
  int id = blockIdx.x;
  int xcd = id & 7, slot = id >> 3;
  int g = slot >> 4, wi = slot & 15;
  int bx = (xcd & 3) * 4 + (wi & 3);
  int by = ((xcd >> 2) * 2 + g) * 4 + (wi >> 2);
  int b0 = bx * 128, j0 = by * 64;
  int tid = threadIdx.x;
  int lane = tid & 63, wave = tid >> 6;
  int wm = wave >> 1, wn = wave & 1;  // 4 M-quarters x 2 N-halves
  int brow = tid >> 3, bc = tid & 7;
  f32x4 acc[2][2] = {};
  for (int k0 = 0; k0 < 1024; k0 += 64) {
    // A: 2 chunks per thread
#pragma unroll
    for (int i = 0; i < 2; ++i) {
      int chunk = tid * 2 + i;
      int row = chunk >> 3, c = chunk & 7;
      size_t go = (size_t)(b0 + row) * 1024 + k0 + c * 8;
      bf16x8 vh = *(const bf16x8*)&X1hi[go];
      bf16x8 vl = *(const bf16x8*)&X1lo[go];
      int d = row * 64 + ((c ^ (row & 7)) << 3);
      *(bf16x8*)&lAhi[d] = vh;
      *(bf16x8*)&lAlo[d] = vl;
    }
    // B: 1 chunk of 8 fp32, trunc split
    {
      const float* src = &W2[(size_t)(j0 + brow) * 1024 + k0 + bc * 8];
      float4 f0 = *(const float4*)src;
      float4 f1 = *(const float4*)(src + 4);
      float e[8] = {f0.x, f0.y, f0.z, f0.w, f1.x, f1.y, f1.z, f1.w};
      bf16x8 hh, ll;
#pragma unroll
      for (int q = 0; q < 8; ++q) {
        short h, l;
        split2(e[q], h, l);
        hh[q] = h;
        ll[q] = l;
      }
      int d = brow * 64 + ((bc ^ (brow & 7)) << 3);
      *(bf16x8*)&lBhi[d] = hh;
      *(bf16x8*)&lBlo[d] = ll;
    }
    __syncthreads();
#pragma unroll
    for (int kk = 0; kk < 2; ++kk) {
      int ch = kk * 4 + (lane >> 4);
      bf16x8 ah[2], al[2], bh[2], bl[2];
#pragma unroll
      for (int mi = 0; mi < 2; ++mi) {
        int rr = wm * 32 + mi * 16 + (lane & 15);
        int ad = rr * 64 + ((ch ^ (rr & 7)) << 3);
        ah[mi] = *(const bf16x8*)&lAhi[ad];
        al[mi] = *(const bf16x8*)&lAlo[ad];
      }
#pragma unroll
      for (int ni = 0; ni < 2; ++ni) {
        int rr = wn * 32 + ni * 16 + (lane & 15);
        int bd = rr * 64 + ((ch ^ (rr & 7)) << 3);
        bh[ni] = *(const bf16x8*)&lBhi[bd];
        bl[ni] = *(const bf16x8*)&lBlo[bd];
      }
#pragma unroll
      for (int mi = 0; mi < 2; ++mi)
#pragma unroll
        for (int ni = 0; ni < 2; ++ni) {
          acc[mi][ni] = __builtin_amdgcn_mfma_f32_16x16x32_bf16(
              ah[mi], bh[ni], acc[mi][ni], 0, 0, 0);
          acc[mi][ni] = __builtin_amdgcn_mfma_f32_16x16x32_bf16(
              al[mi], bh[ni], acc[mi][ni], 0, 0, 0);
          acc[mi][ni] = __builtin_amdgcn_mfma_f32_16x16x32_bf16(
              ah[mi], bl[ni], acc[mi][ni], 0, 0, 0);
        }
    }
    __syncthreads();
  }
#pragma unroll
  for (int mi = 0; mi < 2; ++mi)
#pragma unroll
    for (int ni = 0; ni < 2; ++ni) {
      int col = j0 + wn * 32 + ni * 16 + (lane & 15);
#pragma unroll
      for (int r = 0; r < 4; ++r) {
        int row = b0 + wm * 32 + mi * 16 + (lane >> 4) * 4 + r;
        Y2[(size_t)row * 1024 + col] = acc[mi][ni][r];
      }
    }
#pragma unroll
  for (int ni = 0; ni < 2; ++ni) {
    float s = 0.f, q = 0.f;
#pragma unroll
    for (int mi = 0; mi < 2; ++mi)
#pragma unroll
      for (int r = 0; r < 4; ++r) {
        float v = acc[mi][ni][r];
        s += v;
        q += v * v;
      }
    s += __shfl_xor(s, 16);
    q += __shfl_xor(q, 16);
    s += __shfl_xor(s, 32);
    q += __shfl_xor(q, 32);
    if ((lane >> 4) == 0) {
      int col = j0 + wn * 32 + ni * 16 + lane;
      atomicAdd(&sA2[col], s);
      atomicAdd(&qA2[col], q);
    }
  }
}

// ---------------- k4w: W3 -> bf16 hi/lo [n][k] (padded 160) + BN2 coefs ----------------
__global__ __launch_bounds__(256) void k4w(
    const float* __restrict__ W3, const float* __restrict__ sA2,
    const float* __restrict__ qA2, const float* __restrict__ g2,
    const float* __restrict__ be2, ushort* __restrict__ W3hi,
    ushort* __restrict__ W3lo, float* __restrict__ scale2,
    float* __restrict__ shift2) {
  int n = blockIdx.x;
  int tid = threadIdx.x;
  if (n < 160) {
    int c = tid * 4;
    float4 v = make_float4(0.f, 0.f, 0.f, 0.f);
    if (n < 150) v = *(const float4*)&W3[(size_t)n * 1024 + c];
    float e[4] = {v.x, v.y, v.z, v.w};
    short hh[4], ll[4];
#pragma unroll
    for (int q = 0; q < 4; ++q) split2(e[q], hh[q], ll[q]);
    *(ushort4*)&W3hi[(size_t)n * 1024 + c] =
        make_ushort4((ushort)hh[0], (ushort)hh[1], (ushort)hh[2], (ushort)hh[3]);
    *(ushort4*)&W3lo[(size_t)n * 1024 + c] =
        make_ushort4((ushort)ll[0], (ushort)ll[1], (ushort)ll[2], (ushort)ll[3]);
  } else {
    int j = tid * 4;
#pragma unroll
    for (int q = 0; q < 4; ++q) {
      float sc, sh;
      bn_coef(sA2[j + q], qA2[j + q], g2[j + q], be2[j + q], sc, sh);
      scale2[j + q] = sc;
      shift2[j + q] = sh;
    }
  }
}

// ---------------- k4: MFMA GEMM3, inline BN2+ReLU on A, atomic into Y3 ----------------
__global__ __launch_bounds__(256) void k4_mfma(
    const float* __restrict__ Y2, const float* __restrict__ scale2,
    const float* __restrict__ shift2, const ushort* __restrict__ W3hi,
    const ushort* __restrict__ W3lo, float* __restrict__ Y3) {
  __shared__ short lAhi[32 * 64], lAlo[32 * 64];
  int b0 = blockIdx.x * 32;
  int kb = blockIdx.y * 128;
  int tid = threadIdx.x;
  int lane = tid & 63, wave = tid >> 6;
  int wm = wave & 1, wn = wave >> 1;
  f32x4 acc[5] = {};
  int srow = tid >> 3, sch = tid & 7;
  for (int k0 = 0; k0 < 128; k0 += 64) {
    int kg = kb + k0 + sch * 8;
    const float* src = &Y2[(size_t)(b0 + srow) * 1024 + kg];
    float4 f0 = *(const float4*)src;
    float4 f1 = *(const float4*)(src + 4);
    float4 c0 = *(const float4*)&scale2[kg];
    float4 c1 = *(const float4*)&scale2[kg + 4];
    float4 s0 = *(const float4*)&shift2[kg];
    float4 s1 = *(const float4*)&shift2[kg + 4];
    float e[8] = {f0.x, f0.y, f0.z, f0.w, f1.x, f1.y, f1.z, f1.w};
    float cs[8] = {c0.x, c0.y, c0.z, c0.w, c1.x, c1.y, c1.z, c1.w};
    float sh[8] = {s0.x, s0.y, s0.z, s0.w, s1.x, s1.y, s1.z, s1.w};
    bf16x8 hh, ll;
#pragma unroll
    for (int q = 0; q < 8; ++q) {
      float x = fmaxf(0.f, fmaf(e[q], cs[q], sh[q]));
      short h, l;
      split2(x, h, l);
      hh[q] = h;
      ll[q] = l;
    }
    if (k0) __syncthreads();
    int d = srow * 64 + ((sch ^ (srow & 7)) << 3);
    *(bf16x8*)&lAhi[d] = hh;
    *(bf16x8*)&lAlo[d] = ll;
    __syncthreads();
#pragma unroll
    for (int kk = 0; kk < 2; ++kk) {
      int r = wm * 16 + (lane & 15);
      int ch = kk * 4 + (lane >> 4);
      int ad = r * 64 + ((ch ^ (r & 7)) << 3);
      bf16x8 ah = *(const bf16x8*)&lAhi[ad];
      bf16x8 al = *(const bf16x8*)&lAlo[ad];
#pragma unroll
      for (int ni = 0; ni < 5; ++ni) {
        int col = wn * 80 + ni * 16 + (lane & 15);
        size_t wo = (size_t)col * 1024 + kb + k0 + kk * 32 + (lane >> 4) * 8;
        bf16x8 bh = *(const bf16x8*)&W3hi[wo];
        bf16x8 bl = *(const bf16x8*)&W3lo[wo];
        acc[ni] = __builtin_amdgcn_mfma_f32_16x16x32_bf16(ah, bh, acc[ni], 0, 0, 0);
        acc[ni] = __builtin_amdgcn_mfma_f32_16x16x32_bf16(al, bh, acc[ni], 0, 0, 0);
        acc[ni] = __builtin_amdgcn_mfma_f32_16x16x32_bf16(ah, bl, acc[ni], 0, 0, 0);
      }
    }
  }
#pragma unroll
  for (int ni = 0; ni < 5; ++ni) {
    int col = wn * 80 + ni * 16 + (lane & 15);
    if (col < 150) {
#pragma unroll
      for (int r = 0; r < 4; ++r) {
        int row = b0 + wm * 16 + (lane >> 4) * 4 + r;
        atomicAdd(&Y3[(size_t)row * 150 + col], acc[ni][r]);
      }
    }
  }
}

// ---------------- k5s: raw Y3 column stats -> atomic accumulators ----------------
__global__ __launch_bounds__(256) void k5s(const float* __restrict__ Y3,
                                           float* __restrict__ sA3,
                                           float* __restrict__ qA3) {
  int r0 = blockIdx.x * 8;
  int j = threadIdx.x;
  if (j >= 150) return;
  float s = 0.f, q = 0.f;
  for (int r = 0; r < 8; ++r) {
    float v = Y3[(size_t)(r0 + r) * 150 + j];
    s += v;
    q += v * v;
  }
  atomicAdd(&sA3[j], s);
  atomicAdd(&qA3[j], q);
}

// ---------------- k6a: BN3+ReLU + ct1 + composite(ct2*ct3*cf) -> pre-struct ----------------
__global__ __launch_bounds__(256) void k6a(
    const float* __restrict__ Y3, const float* __restrict__ sA3,
    const float* __restrict__ qA3, const float* __restrict__ g3,
    const float* __restrict__ be3, const float* __restrict__ ct1_w,
    const float* __restrict__ ct1_b, const float* __restrict__ ct2_w,
    const float* __restrict__ ct2_b, const float* __restrict__ ct3_w,
    const float* __restrict__ ct3_b, const float* __restrict__ cf_w,
    const float* __restrict__ cf_b, float* __restrict__ Spre) {
  __shared__ float wt1[32], wb1[4], wt2L[80], wb2L[4], w3fL[20];
  __shared__ float Cc[36], cfb2C[1], cfbraw[1];
  __shared__ float h0p[4][160];
  __shared__ float hA[4][4][312];
  __shared__ float Srow[4][304];
  int tid = threadIdx.x;
  // stage 1: raw weights + ct3*cf fold
  if (tid < 32) wt1[tid] = ct1_w[tid];
  else if (tid < 36) wb1[tid - 32] = ct1_b[tid - 32];
  else if (tid < 116) wt2L[tid - 36] = ct2_w[tid - 36];
  else if (tid < 120) wb2L[tid - 116] = ct2_b[tid - 116];
  else if (tid < 140) {
    int i = (tid - 120) / 5, j = (tid - 120) % 5;
    float s = 0.f;
#pragma unroll
    for (int p = 0; p < 4; ++p) s += cf_w[p] * ct3_w[(i * 4 + p) * 5 + j];
    w3fL[tid - 120] = s;
  } else if (tid == 140) {
    float s = cf_b[0];
#pragma unroll
    for (int p = 0; p < 4; ++p) s += cf_w[p] * ct3_b[p];
    cfbraw[0] = s;
  }
  int w = tid >> 6;
  int lane = tid & 63;
  int r = blockIdx.x * 4 + w;
  // h0p load (independent of stage1)
  for (int i = lane; i < 160; i += 64) {
    int k = i - 2;
    float v = 0.f;
    if (k >= 0 && k < 150) {
      float sc, sh;
      bn_coef(sA3[k], qA3[k], g3[k], be3[k], sc, sh);
      v = fmaxf(0.f, Y3[(size_t)r * 150 + k] * sc + sh);
    }
    h0p[w][i] = v;
  }
  if (lane < 12) {
    int z = (lane < 4) ? lane : (300 + lane);  // 0..3, 304..311
#pragma unroll
    for (int o = 0; o < 4; ++o) hA[w][o][z] = 0.f;
  }
  __syncthreads();
  // stage 2: composite kernel C[i][u] = sum_o sum_{j1+j2=u} wt2[i,o,j1]*w3f[o,j2]
  if (tid < 36) {
    int i = tid / 9, u = tid % 9;
    float s = 0.f;
#pragma unroll
    for (int o = 0; o < 4; ++o) {
      int j2lo = (u > 4) ? (u - 4) : 0;
      int j2hi = (u < 4) ? u : 4;
      for (int j2 = j2lo; j2 <= j2hi; ++j2)
        s += wt2L[(i * 4 + o) * 5 + (u - j2)] * w3fL[o * 5 + j2];
    }
    Cc[tid] = s;
  } else if (tid == 36) {
    float s = cfbraw[0];
#pragma unroll
    for (int o = 0; o < 4; ++o) {
      float t = 0.f;
#pragma unroll
      for (int j2 = 0; j2 < 5; ++j2) t += w3fL[o * 5 + j2];
      s += wb2L[o] * t;
    }
    cfb2C[0] = s;
  }
  __syncthreads();
  // ct1 (stride-2, parity-resolved) -> hA[w][o][4+t]
  for (int t = lane; t < 300; t += 64) {
    int p1 = (t + 3) & 1;
    int base = (t + 3 - p1) >> 1;
    float x0 = h0p[w][2 + base];
    float x1 = h0p[w][1 + base];
    float x2 = h0p[w][base];
    float x3 = h0p[w][base - 1];
#pragma unroll
    for (int o = 0; o < 4; ++o) {
      float acc = wb1[o];
      acc += wt1[o * 8 + p1] * x0;
      acc += wt1[o * 8 + p1 + 2] * x1;
      acc += wt1[o * 8 + p1 + 4] * x2;
      acc += wt1[o * 8 + p1 + 6] * x3;
      hA[w][o][4 + t] = acc;
    }
  }
  __syncthreads();
  // composite 9-tap conv + boundary corrections
  for (int t = lane; t < 300; t += 64) {
    float acc = cfb2C[0];
#pragma unroll
    for (int i = 0; i < 4; ++i)
#pragma unroll
      for (int u = 0; u < 9; ++u) acc += Cc[i * 9 + u] * hA[w][i][t + 8 - u];
    if (t < 2) {
      for (int j2 = t + 3; j2 <= 4; ++j2) {
        int tp_ = t + 2 - j2;  // -1 or -2
        float corr = 0.f;
        for (int o = 0; o < 4; ++o) {
          float hb = wb2L[o];
          for (int i2 = 0; i2 < 4; ++i2)
            for (int j1 = 0; j1 < 5; ++j1)
              hb += wt2L[(i2 * 4 + o) * 5 + j1] * hA[w][i2][6 + tp_ - j1];
          corr += w3fL[o * 5 + j2] * hb;
        }
        acc -= corr;
      }
    }
    if (t > 297) {
      for (int j2 = 0; j2 <= t - 298; ++j2) {
        int tp_ = t + 2 - j2;  // 300 or 301
        float corr = 0.f;
        for (int o = 0; o < 4; ++o) {
          float hb = wb2L[o];
          for (int i2 = 0; i2 < 4; ++i2)
            for (int j1 = 0; j1 < 5; ++j1)
              hb += wt2L[(i2 * 4 + o) * 5 + j1] * hA[w][i2][6 + tp_ - j1];
          corr += w3fL[o * 5 + j2] * hb;
        }
        acc -= corr;
      }
    }
    Srow[w][t] = acc;
  }
  __syncthreads();
  for (int cc = lane; cc < 100; cc += 64) {
    float s0 = Srow[w][3 * cc], s1 = Srow[w][3 * cc + 1], s2 = Srow[w][3 * cc + 2];
    float4 p;
    p.x = s0 * s0;
    p.y = s1 * s1;
    p.z = s2 * s2;
    p.w = 0.f;
    *(float4*)&Spre[((size_t)r * 100 + cc) * 4] = p;
  }
}

// ---------------- k6b: lorentz, cc-split x4, wave-uniform scalar loads ----------------
__global__ __launch_bounds__(320) void k6b(const float* __restrict__ Spre,
                                           float* __restrict__ out) {
  int b = blockIdx.x;
  int l = threadIdx.x;
  float wl = 0.8f + (float)l * (1.0f / 300.0f);
  float w2l = wl * wl;
  float acc = 0.f;
  const float4* pp = (const float4*)&Spre[(size_t)b * 400] + blockIdx.y * 25;
#pragma unroll 5
  for (int cc = 0; cc < 25; ++cc) {
    float4 p = pp[cc];
    float wp2 = p.x, s1sq = p.y, s2sq = p.z;
    float sub1 = s1sq - w2l;
    float denom = fmaf(sub1, sub1, w2l * s2sq);
    float inv = __builtin_amdgcn_rcpf(denom);
    float u = wp2 * inv;
    float tp = u * (wp2 + sub1);
    float tm = u * (wp2 - sub1);
    float n = 0.70710678f * __builtin_amdgcn_sqrtf(fmaxf(tp, 0.f));
    float np1 = n + 1.0f;
    float den2 = fmaf(np1, np1, 0.5f * fmaxf(tm, 0.f));
    acc = fmaf(4.0f * n, __builtin_amdgcn_rcpf(den2), acc);
  }
  if (l < 300) atomicAdd(&out[(size_t)b * 300 + l], acc);
}

extern "C" void kernel_launch(void* const* d_in, const int* in_sizes, int n_in,
                              void* d_out, int out_size, void* d_ws,
                              size_t ws_size, hipStream_t stream) {
  const float* G = (const float*)d_in[0];
  const float* w1 = (const float*)d_in[1];
  const float* g1 = (const float*)d_in[3];
  const float* be1 = (const float*)d_in[4];
  const float* w2 = (const float*)d_in[5];
  const float* g2 = (const float*)d_in[7];
  const float* be2 = (const float*)d_in[8];
  const float* w3 = (const float*)d_in[9];
  const float* g3 = (const float*)d_in[11];
  const float* be3 = (const float*)d_in[12];
  const float* ct1_w = (const float*)d_in[13];
  const float* ct1_b = (const float*)d_in[14];
  const float* ct2_w = (const float*)d_in[15];
  const float* ct2_b = (const float*)d_in[16];
  const float* ct3_w = (const float*)d_in[17];
  const float* ct3_b = (const float*)d_in[18];
  const float* cf_w = (const float*)d_in[19];
  const float* cf_b = (const float*)d_in[20];
  float* out = (float*)d_out;

  float* ws = (float*)d_ws;
  float* Y2 = ws;
  ushort* X1hi = (ushort*)(ws + 2097152);
  ushort* W3hi = (ushort*)(ws + 2097152);
  ushort* W3lo = (ushort*)(ws + 2179072);
  float* scale2 = ws + 2260992;
  float* shift2 = ws + 2262016;
  float* Spre = ws + 2097152;
  ushort* X1lo = (ushort*)(ws + 3145728);
  float* Y3 = ws + 3887104;
  float* sA1 = ws + 4194304;
  float* qA1 = sA1 + 1024;
  float* sA2 = sA1 + 2048;
  float* qA2 = sA1 + 3072;
  float* sA3 = sA1 + 4096;
  float* qA3 = sA1 + 4288;

  hipMemsetAsync(sA1, 0, 4448 * sizeof(float), stream);
  hipMemsetAsync(out, 0, (size_t)out_size * sizeof(float), stream);

  k1s<<<256, 256, 0, stream>>>(G, w1, sA1, qA1);
  k1c<<<256, 256, 0, stream>>>(G, w1, sA1, qA1, g1, be1, X1hi, X1lo);
  k2_mfma<<<256, 512, 0, stream>>>(X1hi, X1lo, w2, Y2, sA2, qA2);
  hipMemsetAsync(Y3, 0, 307200 * sizeof(float), stream);
  k4w<<<161, 256, 0, stream>>>(w3, sA2, qA2, g2, be2, W3hi, W3lo, scale2, shift2);
  k4_mfma<<<dim3(64, 8), 256, 0, stream>>>(Y2, scale2, shift2, W3hi, W3lo, Y3);
  k5s<<<256, 256, 0, stream>>>(Y3, sA3, qA3);
  k6a<<<512, 256, 0, stream>>>(Y3, sA3, qA3, g3, be3, ct1_w, ct1_b, ct2_w,
                               ct2_b, ct3_w, ct3_b, cf_w, cf_b, Spre);
  k6b<<<dim3(2048, 4), 320, 0, stream>>>(Spre, out);
}

// Round 9
// 156.689 us; speedup vs baseline: 1.8189x; 1.0283x over previous
//
#include <hip/hip_runtime.h>
#include <hip/hip_bf16.h>

#define EPS 1e-5f

typedef __attribute__((ext_vector_type(8))) short bf16x8;
typedef __attribute__((ext_vector_type(4))) float f32x4;

// truncation-based hi/lo bf16 split: hi = trunc16(x), lo = trunc16(x - hi)
__device__ __forceinline__ void split2(float x, short& h, short& l) {
  unsigned u = __float_as_uint(x);
  h = (short)(u >> 16);
  float hf = __uint_as_float(u & 0xFFFF0000u);
  l = (short)(__float_as_uint(x - hf) >> 16);
}
__device__ __forceinline__ void bn_coef(float s, float q, float g, float be,
                                        float& sc, float& sh) {
  float mu = s * (1.f / 2048.f);
  float var = q * (1.f / 2048.f) - mu * mu;
  sc = g * rsqrtf(var + EPS);
  sh = be - mu * sc;
}

// ---------------- kzero0: zero out (614400 f) + stat accumulators (4448 f) ----------------
__global__ __launch_bounds__(256) void kzero0(float4* __restrict__ outv,
                                              float4* __restrict__ stv) {
  int idx = blockIdx.x * 256 + threadIdx.x;
  float4 z = make_float4(0.f, 0.f, 0.f, 0.f);
  if (idx < 153600) outv[idx] = z;
  else if (idx < 154712) stv[idx - 153600] = z;
}

// ---------------- k1s: layer1 raw stats -> atomic accumulators ----------------
__global__ __launch_bounds__(256) void k1s(const float* __restrict__ G,
                                           const float* __restrict__ W1,
                                           float* __restrict__ sA1,
                                           float* __restrict__ qA1) {
  int r0 = blockIdx.x * 8;
  int c = threadIdx.x * 4;
  float w[4][8];
#pragma unroll
  for (int q = 0; q < 4; ++q)
#pragma unroll
    for (int k = 0; k < 8; ++k) w[q][k] = W1[(c + q) * 8 + k];
  float s[4] = {}, ss[4] = {};
  for (int r = 0; r < 8; ++r) {
    const float4 g0 = *(const float4*)&G[(size_t)(r0 + r) * 8];
    const float4 g1 = *(const float4*)&G[(size_t)(r0 + r) * 8 + 4];
    float gr[8] = {g0.x, g0.y, g0.z, g0.w, g1.x, g1.y, g1.z, g1.w};
#pragma unroll
    for (int q = 0; q < 4; ++q) {
      float acc = 0.f;
#pragma unroll
      for (int k = 0; k < 8; ++k) acc += gr[k] * w[q][k];
      s[q] += acc;
      ss[q] += acc * acc;
    }
  }
#pragma unroll
  for (int q = 0; q < 4; ++q) {
    atomicAdd(&sA1[c + q], s[q]);
    atomicAdd(&qA1[c + q], ss[q]);
  }
}

// ---------------- k1c: recompute raw Y1, inline BN1+ReLU, split bf16 hi/lo ----------------
__global__ __launch_bounds__(256) void k1c(
    const float* __restrict__ G, const float* __restrict__ W1,
    const float* __restrict__ sA1, const float* __restrict__ qA1,
    const float* __restrict__ g1, const float* __restrict__ be1,
    ushort* __restrict__ X1hi, ushort* __restrict__ X1lo) {
  int r0 = blockIdx.x * 8;
  int c = threadIdx.x * 4;
  float w[4][8];
#pragma unroll
  for (int q = 0; q < 4; ++q)
#pragma unroll
    for (int k = 0; k < 8; ++k) w[q][k] = W1[(c + q) * 8 + k];
  float sc[4], sh[4];
#pragma unroll
  for (int q = 0; q < 4; ++q)
    bn_coef(sA1[c + q], qA1[c + q], g1[c + q], be1[c + q], sc[q], sh[q]);
  for (int r = 0; r < 8; ++r) {
    const float4 g0 = *(const float4*)&G[(size_t)(r0 + r) * 8];
    const float4 g1v = *(const float4*)&G[(size_t)(r0 + r) * 8 + 4];
    float gr[8] = {g0.x, g0.y, g0.z, g0.w, g1v.x, g1v.y, g1v.z, g1v.w};
    short hs[4], ls[4];
#pragma unroll
    for (int q = 0; q < 4; ++q) {
      float acc = 0.f;
#pragma unroll
      for (int k = 0; k < 8; ++k) acc += gr[k] * w[q][k];
      float x = fmaxf(0.f, acc * sc[q] + sh[q]);
      split2(x, hs[q], ls[q]);
    }
    size_t o = (size_t)(r0 + r) * 1024 + c;
    *(ushort4*)&X1hi[o] = make_ushort4((ushort)hs[0], (ushort)hs[1],
                                       (ushort)hs[2], (ushort)hs[3]);
    *(ushort4*)&X1lo[o] = make_ushort4((ushort)ls[0], (ushort)ls[1],
                                       (ushort)ls[2], (ushort)ls[3]);
  }
}

// ---------------- k2: MFMA bf16 hi/lo GEMM2, 8 waves, fused stats ----------------
__global__ __launch_bounds__(512) void k2_mfma(
    const ushort* __restrict__ X1hi, const ushort* __restrict__ X1lo,
    const float* __restrict__ W2, float* __restrict__ Y2,
    float* __restrict__ sA2, float* __restrict__ qA2) {
  __shared__ short lAhi[128 * 64], lAlo[128 * 64];
  __shared__ short lBhi[64 * 64], lBlo[64 * 64];
  int id = blockIdx.x;
  int xcd = id & 7, slot = id >> 3;
  int g = slot >> 4, wi = slot & 15;
  int bx = (xcd & 3) * 4 + (wi & 3);
  int by = ((xcd >> 2) * 2 + g) * 4 + (wi >> 2);
  int b0 = bx * 128, j0 = by * 64;
  int tid = threadIdx.x;
  int lane = tid & 63, wave = tid >> 6;
  int wm = wave >> 1, wn = wave & 1;
  int brow = tid >> 3, bc = tid & 7;
  f32x4 acc[2][2] = {};
  for (int k0 = 0; k0 < 1024; k0 += 64) {
#pragma unroll
    for (int i = 0; i < 2; ++i) {
      int chunk = tid * 2 + i;
      int row = chunk >> 3, c = chunk & 7;
      size_t go = (size_t)(b0 + row) * 1024 + k0 + c * 8;
      bf16x8 vh = *(const bf16x8*)&X1hi[go];
      bf16x8 vl = *(const bf16x8*)&X1lo[go];
      int d = row * 64 + ((c ^ (row & 7)) << 3);
      *(bf16x8*)&lAhi[d] = vh;
      *(bf16x8*)&lAlo[d] = vl;
    }
    {
      const float* src = &W2[(size_t)(j0 + brow) * 1024 + k0 + bc * 8];
      float4 f0 = *(const float4*)src;
      float4 f1 = *(const float4*)(src + 4);
      float e[8] = {f0.x, f0.y, f0.z, f0.w, f1.x, f1.y, f1.z, f1.w};
      bf16x8 hh, ll;
#pragma unroll
      for (int q = 0; q < 8; ++q) {
        short h, l;
        split2(e[q], h, l);
        hh[q] = h;
        ll[q] = l;
      }
      int d = brow * 64 + ((bc ^ (brow & 7)) << 3);
      *(bf16x8*)&lBhi[d] = hh;
      *(bf16x8*)&lBlo[d] = ll;
    }
    __syncthreads();
#pragma unroll
    for (int kk = 0; kk < 2; ++kk) {
      int ch = kk * 4 + (lane >> 4);
      bf16x8 ah[2], al[2], bh[2], bl[2];
#pragma unroll
      for (int mi = 0; mi < 2; ++mi) {
        int rr = wm * 32 + mi * 16 + (lane & 15);
        int ad = rr * 64 + ((ch ^ (rr & 7)) << 3);
        ah[mi] = *(const bf16x8*)&lAhi[ad];
        al[mi] = *(const bf16x8*)&lAlo[ad];
      }
#pragma unroll
      for (int ni = 0; ni < 2; ++ni) {
        int rr = wn * 32 + ni * 16 + (lane & 15);
        int bd = rr * 64 + ((ch ^ (rr & 7)) << 3);
        bh[ni] = *(const bf16x8*)&lBhi[bd];
        bl[ni] = *(const bf16x8*)&lBlo[bd];
      }
#pragma unroll
      for (int mi = 0; mi < 2; ++mi)
#pragma unroll
        for (int ni = 0; ni < 2; ++ni) {
          acc[mi][ni] = __builtin_amdgcn_mfma_f32_16x16x32_bf16(
              ah[mi], bh[ni], acc[mi][ni], 0, 0, 0);
          acc[mi][ni] = __builtin_amdgcn_mfma_f32_16x16x32_bf16(
              al[mi], bh[ni], acc[mi][ni], 0, 0, 0);
          acc[mi][ni] = __builtin_amdgcn_mfma_f32_16x16x32_bf16(
              ah[mi], bl[ni], acc[mi][ni], 0, 0, 0);
        }
    }
    __syncthreads();
  }
#pragma unroll
  for (int mi = 0; mi < 2; ++mi)
#pragma unroll
    for (int ni = 0; ni < 2; ++ni) {
      int col = j0 + wn * 32 + ni * 16 + (lane & 15);
#pragma unroll
      for (int r = 0; r < 4; ++r) {
        int row = b0 + wm * 32 + mi * 16 + (lane >> 4) * 4 + r;
        Y2[(size_t)row * 1024 + col] = acc[mi][ni][r];
      }
    }
#pragma unroll
  for (int ni = 0; ni < 2; ++ni) {
    float s = 0.f, q = 0.f;
#pragma unroll
    for (int mi = 0; mi < 2; ++mi)
#pragma unroll
      for (int r = 0; r < 4; ++r) {
        float v = acc[mi][ni][r];
        s += v;
        q += v * v;
      }
    s += __shfl_xor(s, 16);
    q += __shfl_xor(q, 16);
    s += __shfl_xor(s, 32);
    q += __shfl_xor(q, 32);
    if ((lane >> 4) == 0) {
      int col = j0 + wn * 32 + ni * 16 + lane;
      atomicAdd(&sA2[col], s);
      atomicAdd(&qA2[col], q);
    }
  }
}

// ---------------- k4w: W3 -> bf16 hi/lo + BN2 coefs + zero Y3 ----------------
// grid 461: [0,160) W3 split | 160 BN coefs | [161,461) zero Y3 (1024 f each)
__global__ __launch_bounds__(256) void k4w(
    const float* __restrict__ W3, const float* __restrict__ sA2,
    const float* __restrict__ qA2, const float* __restrict__ g2,
    const float* __restrict__ be2, ushort* __restrict__ W3hi,
    ushort* __restrict__ W3lo, float* __restrict__ scale2,
    float* __restrict__ shift2, float4* __restrict__ Y3v) {
  int n = blockIdx.x;
  int tid = threadIdx.x;
  if (n < 160) {
    int c = tid * 4;
    float4 v = make_float4(0.f, 0.f, 0.f, 0.f);
    if (n < 150) v = *(const float4*)&W3[(size_t)n * 1024 + c];
    float e[4] = {v.x, v.y, v.z, v.w};
    short hh[4], ll[4];
#pragma unroll
    for (int q = 0; q < 4; ++q) split2(e[q], hh[q], ll[q]);
    *(ushort4*)&W3hi[(size_t)n * 1024 + c] =
        make_ushort4((ushort)hh[0], (ushort)hh[1], (ushort)hh[2], (ushort)hh[3]);
    *(ushort4*)&W3lo[(size_t)n * 1024 + c] =
        make_ushort4((ushort)ll[0], (ushort)ll[1], (ushort)ll[2], (ushort)ll[3]);
  } else if (n == 160) {
    int j = tid * 4;
#pragma unroll
    for (int q = 0; q < 4; ++q) {
      float sc, sh;
      bn_coef(sA2[j + q], qA2[j + q], g2[j + q], be2[j + q], sc, sh);
      scale2[j + q] = sc;
      shift2[j + q] = sh;
    }
  } else {
    Y3v[(n - 161) * 256 + tid] = make_float4(0.f, 0.f, 0.f, 0.f);
  }
}

// ---------------- k4: MFMA GEMM3, inline BN2+ReLU on A, atomic into Y3 ----------------
__global__ __launch_bounds__(256) void k4_mfma(
    const float* __restrict__ Y2, const float* __restrict__ scale2,
    const float* __restrict__ shift2, const ushort* __restrict__ W3hi,
    const ushort* __restrict__ W3lo, float* __restrict__ Y3) {
  __shared__ short lAhi[32 * 64], lAlo[32 * 64];
  int b0 = blockIdx.x * 32;
  int kb = blockIdx.y * 128;
  int tid = threadIdx.x;
  int lane = tid & 63, wave = tid >> 6;
  int wm = wave & 1, wn = wave >> 1;
  f32x4 acc[5] = {};
  int srow = tid >> 3, sch = tid & 7;
  for (int k0 = 0; k0 < 128; k0 += 64) {
    int kg = kb + k0 + sch * 8;
    const float* src = &Y2[(size_t)(b0 + srow) * 1024 + kg];
    float4 f0 = *(const float4*)src;
    float4 f1 = *(const float4*)(src + 4);
    float4 c0 = *(const float4*)&scale2[kg];
    float4 c1 = *(const float4*)&scale2[kg + 4];
    float4 s0 = *(const float4*)&shift2[kg];
    float4 s1 = *(const float4*)&shift2[kg + 4];
    float e[8] = {f0.x, f0.y, f0.z, f0.w, f1.x, f1.y, f1.z, f1.w};
    float cs[8] = {c0.x, c0.y, c0.z, c0.w, c1.x, c1.y, c1.z, c1.w};
    float sh[8] = {s0.x, s0.y, s0.z, s0.w, s1.x, s1.y, s1.z, s1.w};
    bf16x8 hh, ll;
#pragma unroll
    for (int q = 0; q < 8; ++q) {
      float x = fmaxf(0.f, fmaf(e[q], cs[q], sh[q]));
      short h, l;
      split2(x, h, l);
      hh[q] = h;
      ll[q] = l;
    }
    if (k0) __syncthreads();
    int d = srow * 64 + ((sch ^ (srow & 7)) << 3);
    *(bf16x8*)&lAhi[d] = hh;
    *(bf16x8*)&lAlo[d] = ll;
    __syncthreads();
#pragma unroll
    for (int kk = 0; kk < 2; ++kk) {
      int r = wm * 16 + (lane & 15);
      int ch = kk * 4 + (lane >> 4);
      int ad = r * 64 + ((ch ^ (r & 7)) << 3);
      bf16x8 ah = *(const bf16x8*)&lAhi[ad];
      bf16x8 al = *(const bf16x8*)&lAlo[ad];
#pragma unroll
      for (int ni = 0; ni < 5; ++ni) {
        int col = wn * 80 + ni * 16 + (lane & 15);
        size_t wo = (size_t)col * 1024 + kb + k0 + kk * 32 + (lane >> 4) * 8;
        bf16x8 bh = *(const bf16x8*)&W3hi[wo];
        bf16x8 bl = *(const bf16x8*)&W3lo[wo];
        acc[ni] = __builtin_amdgcn_mfma_f32_16x16x32_bf16(ah, bh, acc[ni], 0, 0, 0);
        acc[ni] = __builtin_amdgcn_mfma_f32_16x16x32_bf16(al, bh, acc[ni], 0, 0, 0);
        acc[ni] = __builtin_amdgcn_mfma_f32_16x16x32_bf16(ah, bl, acc[ni], 0, 0, 0);
      }
    }
  }
#pragma unroll
  for (int ni = 0; ni < 5; ++ni) {
    int col = wn * 80 + ni * 16 + (lane & 15);
    if (col < 150) {
#pragma unroll
      for (int r = 0; r < 4; ++r) {
        int row = b0 + wm * 16 + (lane >> 4) * 4 + r;
        atomicAdd(&Y3[(size_t)row * 150 + col], acc[ni][r]);
      }
    }
  }
}

// ---------------- k5s: raw Y3 column stats -> atomic accumulators ----------------
__global__ __launch_bounds__(256) void k5s(const float* __restrict__ Y3,
                                           float* __restrict__ sA3,
                                           float* __restrict__ qA3) {
  int r0 = blockIdx.x * 8;
  int j = threadIdx.x;
  if (j >= 150) return;
  float s = 0.f, q = 0.f;
  for (int r = 0; r < 8; ++r) {
    float v = Y3[(size_t)(r0 + r) * 150 + j];
    s += v;
    q += v * v;
  }
  atomicAdd(&sA3[j], s);
  atomicAdd(&qA3[j], q);
}

// ---------------- k6a: BN3+ReLU + ct1 + composite(ct2*ct3*cf) -> pre-struct ----------------
__global__ __launch_bounds__(256) void k6a(
    const float* __restrict__ Y3, const float* __restrict__ sA3,
    const float* __restrict__ qA3, const float* __restrict__ g3,
    const float* __restrict__ be3, const float* __restrict__ ct1_w,
    const float* __restrict__ ct1_b, const float* __restrict__ ct2_w,
    const float* __restrict__ ct2_b, const float* __restrict__ ct3_w,
    const float* __restrict__ ct3_b, const float* __restrict__ cf_w,
    const float* __restrict__ cf_b, float* __restrict__ Spre) {
  __shared__ float wt1[32], wb1[4], wt2L[80], wb2L[4], w3fL[20];
  __shared__ float Cc[36], cfb2C[1], cfbraw[1];
  __shared__ float h0p[4][160];
  __shared__ float hA[4][4][312];
  __shared__ float Srow[4][304];
  int tid = threadIdx.x;
  if (tid < 32) wt1[tid] = ct1_w[tid];
  else if (tid < 36) wb1[tid - 32] = ct1_b[tid - 32];
  else if (tid < 116) wt2L[tid - 36] = ct2_w[tid - 36];
  else if (tid < 120) wb2L[tid - 116] = ct2_b[tid - 116];
  else if (tid < 140) {
    int i = (tid - 120) / 5, j = (tid - 120) % 5;
    float s = 0.f;
#pragma unroll
    for (int p = 0; p < 4; ++p) s += cf_w[p] * ct3_w[(i * 4 + p) * 5 + j];
    w3fL[tid - 120] = s;
  } else if (tid == 140) {
    float s = cf_b[0];
#pragma unroll
    for (int p = 0; p < 4; ++p) s += cf_w[p] * ct3_b[p];
    cfbraw[0] = s;
  }
  int w = tid >> 6;
  int lane = tid & 63;
  int r = blockIdx.x * 4 + w;
  for (int i = lane; i < 160; i += 64) {
    int k = i - 2;
    float v = 0.f;
    if (k >= 0 && k < 150) {
      float sc, sh;
      bn_coef(sA3[k], qA3[k], g3[k], be3[k], sc, sh);
      v = fmaxf(0.f, Y3[(size_t)r * 150 + k] * sc + sh);
    }
    h0p[w][i] = v;
  }
  if (lane < 12) {
    int z = (lane < 4) ? lane : (300 + lane);
#pragma unroll
    for (int o = 0; o < 4; ++o) hA[w][o][z] = 0.f;
  }
  __syncthreads();
  if (tid < 36) {
    int i = tid / 9, u = tid % 9;
    float s = 0.f;
#pragma unroll
    for (int o = 0; o < 4; ++o) {
      int j2lo = (u > 4) ? (u - 4) : 0;
      int j2hi = (u < 4) ? u : 4;
      for (int j2 = j2lo; j2 <= j2hi; ++j2)
        s += wt2L[(i * 4 + o) * 5 + (u - j2)] * w3fL[o * 5 + j2];
    }
    Cc[tid] = s;
  } else if (tid == 36) {
    float s = cfbraw[0];
#pragma unroll
    for (int o = 0; o < 4; ++o) {
      float t = 0.f;
#pragma unroll
      for (int j2 = 0; j2 < 5; ++j2) t += w3fL[o * 5 + j2];
      s += wb2L[o] * t;
    }
    cfb2C[0] = s;
  }
  __syncthreads();
  for (int t = lane; t < 300; t += 64) {
    int p1 = (t + 3) & 1;
    int base = (t + 3 - p1) >> 1;
    float x0 = h0p[w][2 + base];
    float x1 = h0p[w][1 + base];
    float x2 = h0p[w][base];
    float x3 = h0p[w][base - 1];
#pragma unroll
    for (int o = 0; o < 4; ++o) {
      float acc = wb1[o];
      acc += wt1[o * 8 + p1] * x0;
      acc += wt1[o * 8 + p1 + 2] * x1;
      acc += wt1[o * 8 + p1 + 4] * x2;
      acc += wt1[o * 8 + p1 + 6] * x3;
      hA[w][o][4 + t] = acc;
    }
  }
  __syncthreads();
  for (int t = lane; t < 300; t += 64) {
    float acc = cfb2C[0];
#pragma unroll
    for (int i = 0; i < 4; ++i)
#pragma unroll
      for (int u = 0; u < 9; ++u) acc += Cc[i * 9 + u] * hA[w][i][t + 8 - u];
    if (t < 2) {
      for (int j2 = t + 3; j2 <= 4; ++j2) {
        int tp_ = t + 2 - j2;
        float corr = 0.f;
        for (int o = 0; o < 4; ++o) {
          float hb = wb2L[o];
          for (int i2 = 0; i2 < 4; ++i2)
            for (int j1 = 0; j1 < 5; ++j1)
              hb += wt2L[(i2 * 4 + o) * 5 + j1] * hA[w][i2][6 + tp_ - j1];
          corr += w3fL[o * 5 + j2] * hb;
        }
        acc -= corr;
      }
    }
    if (t > 297) {
      for (int j2 = 0; j2 <= t - 298; ++j2) {
        int tp_ = t + 2 - j2;
        float corr = 0.f;
        for (int o = 0; o < 4; ++o) {
          float hb = wb2L[o];
          for (int i2 = 0; i2 < 4; ++i2)
            for (int j1 = 0; j1 < 5; ++j1)
              hb += wt2L[(i2 * 4 + o) * 5 + j1] * hA[w][i2][6 + tp_ - j1];
          corr += w3fL[o * 5 + j2] * hb;
        }
        acc -= corr;
      }
    }
    Srow[w][t] = acc;
  }
  __syncthreads();
  for (int cc = lane; cc < 100; cc += 64) {
    float s0 = Srow[w][3 * cc], s1 = Srow[w][3 * cc + 1], s2 = Srow[w][3 * cc + 2];
    float4 p;
    p.x = s0 * s0;
    p.y = s1 * s1;
    p.z = s2 * s2;
    p.w = 0.f;
    *(float4*)&Spre[((size_t)r * 100 + cc) * 4] = p;
  }
}

// ---------------- k6b: lorentz, cc-split x4, wave-uniform scalar loads ----------------
__global__ __launch_bounds__(320) void k6b(const float* __restrict__ Spre,
                                           float* __restrict__ out) {
  int b = blockIdx.x;
  int l = threadIdx.x;
  float wl = 0.8f + (float)l * (1.0f / 300.0f);
  float w2l = wl * wl;
  float acc = 0.f;
  const float4* pp = (const float4*)&Spre[(size_t)b * 400] + blockIdx.y * 25;
#pragma unroll 5
  for (int cc = 0; cc < 25; ++cc) {
    float4 p = pp[cc];
    float wp2 = p.x, s1sq = p.y, s2sq = p.z;
    float sub1 = s1sq - w2l;
    float denom = fmaf(sub1, sub1, w2l * s2sq);
    float inv = __builtin_amdgcn_rcpf(denom);
    float u = wp2 * inv;
    float tp = u * (wp2 + sub1);
    float tm = u * (wp2 - sub1);
    float n = 0.70710678f * __builtin_amdgcn_sqrtf(fmaxf(tp, 0.f));
    float np1 = n + 1.0f;
    float den2 = fmaf(np1, np1, 0.5f * fmaxf(tm, 0.f));
    acc = fmaf(4.0f * n, __builtin_amdgcn_rcpf(den2), acc);
  }
  if (l < 300) atomicAdd(&out[(size_t)b * 300 + l], acc);
}

extern "C" void kernel_launch(void* const* d_in, const int* in_sizes, int n_in,
                              void* d_out, int out_size, void* d_ws,
                              size_t ws_size, hipStream_t stream) {
  const float* G = (const float*)d_in[0];
  const float* w1 = (const float*)d_in[1];
  const float* g1 = (const float*)d_in[3];
  const float* be1 = (const float*)d_in[4];
  const float* w2 = (const float*)d_in[5];
  const float* g2 = (const float*)d_in[7];
  const float* be2 = (const float*)d_in[8];
  const float* w3 = (const float*)d_in[9];
  const float* g3 = (const float*)d_in[11];
  const float* be3 = (const float*)d_in[12];
  const float* ct1_w = (const float*)d_in[13];
  const float* ct1_b = (const float*)d_in[14];
  const float* ct2_w = (const float*)d_in[15];
  const float* ct2_b = (const float*)d_in[16];
  const float* ct3_w = (const float*)d_in[17];
  const float* ct3_b = (const float*)d_in[18];
  const float* cf_w = (const float*)d_in[19];
  const float* cf_b = (const float*)d_in[20];
  float* out = (float*)d_out;

  float* ws = (float*)d_ws;
  float* Y2 = ws;
  ushort* X1hi = (ushort*)(ws + 2097152);
  ushort* W3hi = (ushort*)(ws + 2097152);
  ushort* W3lo = (ushort*)(ws + 2179072);
  float* scale2 = ws + 2260992;
  float* shift2 = ws + 2262016;
  float* Spre = ws + 2097152;
  ushort* X1lo = (ushort*)(ws + 3145728);
  float* Y3 = ws + 3887104;
  float* sA1 = ws + 4194304;
  float* qA1 = sA1 + 1024;
  float* sA2 = sA1 + 2048;
  float* qA2 = sA1 + 3072;
  float* sA3 = sA1 + 4096;
  float* qA3 = sA1 + 4288;

  kzero0<<<605, 256, 0, stream>>>((float4*)out, (float4*)sA1);
  k1s<<<256, 256, 0, stream>>>(G, w1, sA1, qA1);
  k1c<<<256, 256, 0, stream>>>(G, w1, sA1, qA1, g1, be1, X1hi, X1lo);
  k2_mfma<<<256, 512, 0, stream>>>(X1hi, X1lo, w2, Y2, sA2, qA2);
  k4w<<<461, 256, 0, stream>>>(w3, sA2, qA2, g2, be2, W3hi, W3lo, scale2,
                               shift2, (float4*)Y3);
  k4_mfma<<<dim3(64, 8), 256, 0, stream>>>(Y2, scale2, shift2, W3hi, W3lo, Y3);
  k5s<<<256, 256, 0, stream>>>(Y3, sA3, qA3);
  k6a<<<512, 256, 0, stream>>>(Y3, sA3, qA3, g3, be3, ct1_w, ct1_b, ct2_w,
                               ct2_b, ct3_w, ct3_b, cf_w, cf_b, Spre);
  k6b<<<dim3(2048, 4), 320, 0, stream>>>(Spre, out);
}

// Round 10
// 156.618 us; speedup vs baseline: 1.8197x; 1.0005x over previous
//
#include <hip/hip_runtime.h>
#include <hip/hip_bf16.h>

#define EPS 1e-5f

typedef __attribute__((ext_vector_type(8))) short bf16x8;
typedef __attribute__((ext_vector_type(4))) float f32x4;

__device__ __forceinline__ void gload16(const void* g, void* l) {
  __builtin_amdgcn_global_load_lds(
      (const __attribute__((address_space(1))) unsigned int*)g,
      (__attribute__((address_space(3))) unsigned int*)l, 16, 0, 0);
}

// truncation-based hi/lo bf16 split
__device__ __forceinline__ void split2(float x, short& h, short& l) {
  unsigned u = __float_as_uint(x);
  h = (short)(u >> 16);
  float hf = __uint_as_float(u & 0xFFFF0000u);
  l = (short)(__float_as_uint(x - hf) >> 16);
}
__device__ __forceinline__ void bn_coef(float s, float q, float g, float be,
                                        float& sc, float& sh) {
  float mu = s * (1.f / 2048.f);
  float var = q * (1.f / 2048.f) - mu * mu;
  sc = g * rsqrtf(var + EPS);
  sh = be - mu * sc;
}

// ---------------- kzero0: zero out + stat accumulators ----------------
__global__ __launch_bounds__(256) void kzero0(float4* __restrict__ outv,
                                              float4* __restrict__ stv) {
  int idx = blockIdx.x * 256 + threadIdx.x;
  float4 z = make_float4(0.f, 0.f, 0.f, 0.f);
  if (idx < 153600) outv[idx] = z;
  else if (idx < 154712) stv[idx - 153600] = z;
}

// ---------------- k2w: W2 -> bf16 hi/lo, tiled-swizzled [nt][kt] 64x64 ----------------
__global__ __launch_bounds__(256) void k2w(const float* __restrict__ W2,
                                           ushort* __restrict__ W2thi,
                                           ushort* __restrict__ W2tlo) {
  int j = blockIdx.x;
  int c = threadIdx.x * 4;
  int nt = j >> 6, rr = j & 63;
  int kt = c >> 6, chunk = (c >> 3) & 7, e = c & 7;
  float4 v = *(const float4*)&W2[(size_t)j * 1024 + c];
  float ev[4] = {v.x, v.y, v.z, v.w};
  short hh[4], ll[4];
#pragma unroll
  for (int q = 0; q < 4; ++q) split2(ev[q], hh[q], ll[q]);
  size_t o = ((size_t)(nt * 16 + kt) << 12) + rr * 64 + ((chunk ^ (rr & 7)) << 3) + e;
  *(ushort4*)&W2thi[o] = make_ushort4((ushort)hh[0], (ushort)hh[1],
                                      (ushort)hh[2], (ushort)hh[3]);
  *(ushort4*)&W2tlo[o] = make_ushort4((ushort)ll[0], (ushort)ll[1],
                                      (ushort)ll[2], (ushort)ll[3]);
}

// ---------------- k1s: layer1 raw stats -> atomic accumulators ----------------
__global__ __launch_bounds__(256) void k1s(const float* __restrict__ G,
                                           const float* __restrict__ W1,
                                           float* __restrict__ sA1,
                                           float* __restrict__ qA1) {
  int r0 = blockIdx.x * 8;
  int c = threadIdx.x * 4;
  float w[4][8];
#pragma unroll
  for (int q = 0; q < 4; ++q)
#pragma unroll
    for (int k = 0; k < 8; ++k) w[q][k] = W1[(c + q) * 8 + k];
  float s[4] = {}, ss[4] = {};
  for (int r = 0; r < 8; ++r) {
    const float4 g0 = *(const float4*)&G[(size_t)(r0 + r) * 8];
    const float4 g1 = *(const float4*)&G[(size_t)(r0 + r) * 8 + 4];
    float gr[8] = {g0.x, g0.y, g0.z, g0.w, g1.x, g1.y, g1.z, g1.w};
#pragma unroll
    for (int q = 0; q < 4; ++q) {
      float acc = 0.f;
#pragma unroll
      for (int k = 0; k < 8; ++k) acc += gr[k] * w[q][k];
      s[q] += acc;
      ss[q] += acc * acc;
    }
  }
#pragma unroll
  for (int q = 0; q < 4; ++q) {
    atomicAdd(&sA1[c + q], s[q]);
    atomicAdd(&qA1[c + q], ss[q]);
  }
}

// ---------------- k1c: raw Y1, BN1+ReLU, split, write TILED-SWIZZLED ----------------
__global__ __launch_bounds__(256) void k1c(
    const float* __restrict__ G, const float* __restrict__ W1,
    const float* __restrict__ sA1, const float* __restrict__ qA1,
    const float* __restrict__ g1, const float* __restrict__ be1,
    ushort* __restrict__ X1thi, ushort* __restrict__ X1tlo) {
  int r0 = blockIdx.x * 8;
  int c = threadIdx.x * 4;
  float w[4][8];
#pragma unroll
  for (int q = 0; q < 4; ++q)
#pragma unroll
    for (int k = 0; k < 8; ++k) w[q][k] = W1[(c + q) * 8 + k];
  float sc[4], sh[4];
#pragma unroll
  for (int q = 0; q < 4; ++q)
    bn_coef(sA1[c + q], qA1[c + q], g1[c + q], be1[c + q], sc[q], sh[q]);
  int kt = c >> 6, chunk = (c >> 3) & 7, e = c & 7;
  for (int r = 0; r < 8; ++r) {
    int b = r0 + r;
    const float4 g0 = *(const float4*)&G[(size_t)b * 8];
    const float4 g1v = *(const float4*)&G[(size_t)b * 8 + 4];
    float gr[8] = {g0.x, g0.y, g0.z, g0.w, g1v.x, g1v.y, g1v.z, g1v.w};
    short hs[4], ls[4];
#pragma unroll
    for (int q = 0; q < 4; ++q) {
      float acc = 0.f;
#pragma unroll
      for (int k = 0; k < 8; ++k) acc += gr[k] * w[q][k];
      float x = fmaxf(0.f, acc * sc[q] + sh[q]);
      split2(x, hs[q], ls[q]);
    }
    int mt = b >> 7, rr = b & 127;
    size_t o = ((size_t)(mt * 16 + kt) << 13) + rr * 64 + ((chunk ^ (rr & 7)) << 3) + e;
    *(ushort4*)&X1thi[o] = make_ushort4((ushort)hs[0], (ushort)hs[1],
                                        (ushort)hs[2], (ushort)hs[3]);
    *(ushort4*)&X1tlo[o] = make_ushort4((ushort)ls[0], (ushort)ls[1],
                                        (ushort)ls[2], (ushort)ls[3]);
  }
}

// ---------------- k2: MFMA GEMM2, global_load_lds staging, fused stats ----------------
__global__ __launch_bounds__(512) void k2_mfma(
    const ushort* __restrict__ X1thi, const ushort* __restrict__ X1tlo,
    const ushort* __restrict__ W2thi, const ushort* __restrict__ W2tlo,
    float* __restrict__ Y2, float* __restrict__ sA2, float* __restrict__ qA2) {
  __shared__ short lAhi[128 * 64], lAlo[128 * 64];
  __shared__ short lBhi[64 * 64], lBlo[64 * 64];
  int id = blockIdx.x;
  int xcd = id & 7, slot = id >> 3;
  int g = slot >> 4, wi = slot & 15;
  int bx = (xcd & 3) * 4 + (wi & 3);
  int by = ((xcd >> 2) * 2 + g) * 4 + (wi >> 2);
  int b0 = bx * 128, j0 = by * 64;
  int tid = threadIdx.x;
  int lane = tid & 63, wave = tid >> 6;
  int wm = wave >> 1, wn = wave & 1;
  int woff = wave * 1024 + lane * 16;  // per-lane global byte offset
  int loff = wave * 1024;              // wave-uniform LDS byte base
  f32x4 acc[2][2] = {};
  for (int kt = 0; kt < 16; ++kt) {
    const char* ga = (const char*)(X1thi + ((size_t)(bx * 16 + kt) << 13));
    const char* gl = (const char*)(X1tlo + ((size_t)(bx * 16 + kt) << 13));
    const char* gb = (const char*)(W2thi + ((size_t)(by * 16 + kt) << 12));
    const char* gc = (const char*)(W2tlo + ((size_t)(by * 16 + kt) << 12));
    gload16(ga + woff, (char*)lAhi + loff);
    gload16(ga + woff + 8192, (char*)lAhi + loff + 8192);
    gload16(gl + woff, (char*)lAlo + loff);
    gload16(gl + woff + 8192, (char*)lAlo + loff + 8192);
    gload16(gb + woff, (char*)lBhi + loff);
    gload16(gc + woff, (char*)lBlo + loff);
    __syncthreads();
#pragma unroll
    for (int kk = 0; kk < 2; ++kk) {
      int ch = kk * 4 + (lane >> 4);
      bf16x8 ah[2], al[2], bh[2], bl[2];
#pragma unroll
      for (int mi = 0; mi < 2; ++mi) {
        int rr = wm * 32 + mi * 16 + (lane & 15);
        int ad = rr * 64 + ((ch ^ (rr & 7)) << 3);
        ah[mi] = *(const bf16x8*)&lAhi[ad];
        al[mi] = *(const bf16x8*)&lAlo[ad];
      }
#pragma unroll
      for (int ni = 0; ni < 2; ++ni) {
        int rr = wn * 32 + ni * 16 + (lane & 15);
        int bd = rr * 64 + ((ch ^ (rr & 7)) << 3);
        bh[ni] = *(const bf16x8*)&lBhi[bd];
        bl[ni] = *(const bf16x8*)&lBlo[bd];
      }
#pragma unroll
      for (int mi = 0; mi < 2; ++mi)
#pragma unroll
        for (int ni = 0; ni < 2; ++ni) {
          acc[mi][ni] = __builtin_amdgcn_mfma_f32_16x16x32_bf16(
              ah[mi], bh[ni], acc[mi][ni], 0, 0, 0);
          acc[mi][ni] = __builtin_amdgcn_mfma_f32_16x16x32_bf16(
              al[mi], bh[ni], acc[mi][ni], 0, 0, 0);
          acc[mi][ni] = __builtin_amdgcn_mfma_f32_16x16x32_bf16(
              ah[mi], bl[ni], acc[mi][ni], 0, 0, 0);
        }
    }
    __syncthreads();
  }
#pragma unroll
  for (int mi = 0; mi < 2; ++mi)
#pragma unroll
    for (int ni = 0; ni < 2; ++ni) {
      int col = j0 + wn * 32 + ni * 16 + (lane & 15);
#pragma unroll
      for (int r = 0; r < 4; ++r) {
        int row = b0 + wm * 32 + mi * 16 + (lane >> 4) * 4 + r;
        Y2[(size_t)row * 1024 + col] = acc[mi][ni][r];
      }
    }
#pragma unroll
  for (int ni = 0; ni < 2; ++ni) {
    float s = 0.f, q = 0.f;
#pragma unroll
    for (int mi = 0; mi < 2; ++mi)
#pragma unroll
      for (int r = 0; r < 4; ++r) {
        float v = acc[mi][ni][r];
        s += v;
        q += v * v;
      }
    s += __shfl_xor(s, 16);
    q += __shfl_xor(q, 16);
    s += __shfl_xor(s, 32);
    q += __shfl_xor(q, 32);
    if ((lane >> 4) == 0) {
      int col = j0 + wn * 32 + ni * 16 + lane;
      atomicAdd(&sA2[col], s);
      atomicAdd(&qA2[col], q);
    }
  }
}

// ---------------- k4w: W3 -> bf16 hi/lo + BN2 coefs + zero Y3 ----------------
__global__ __launch_bounds__(256) void k4w(
    const float* __restrict__ W3, const float* __restrict__ sA2,
    const float* __restrict__ qA2, const float* __restrict__ g2,
    const float* __restrict__ be2, ushort* __restrict__ W3hi,
    ushort* __restrict__ W3lo, float* __restrict__ scale2,
    float* __restrict__ shift2, float4* __restrict__ Y3v) {
  int n = blockIdx.x;
  int tid = threadIdx.x;
  if (n < 160) {
    int c = tid * 4;
    float4 v = make_float4(0.f, 0.f, 0.f, 0.f);
    if (n < 150) v = *(const float4*)&W3[(size_t)n * 1024 + c];
    float e[4] = {v.x, v.y, v.z, v.w};
    short hh[4], ll[4];
#pragma unroll
    for (int q = 0; q < 4; ++q) split2(e[q], hh[q], ll[q]);
    *(ushort4*)&W3hi[(size_t)n * 1024 + c] =
        make_ushort4((ushort)hh[0], (ushort)hh[1], (ushort)hh[2], (ushort)hh[3]);
    *(ushort4*)&W3lo[(size_t)n * 1024 + c] =
        make_ushort4((ushort)ll[0], (ushort)ll[1], (ushort)ll[2], (ushort)ll[3]);
  } else if (n == 160) {
    int j = tid * 4;
#pragma unroll
    for (int q = 0; q < 4; ++q) {
      float sc, sh;
      bn_coef(sA2[j + q], qA2[j + q], g2[j + q], be2[j + q], sc, sh);
      scale2[j + q] = sc;
      shift2[j + q] = sh;
    }
  } else {
    Y3v[(n - 161) * 256 + tid] = make_float4(0.f, 0.f, 0.f, 0.f);
  }
}

// ---------------- k4: MFMA GEMM3, inline BN2+ReLU on A, atomic into Y3 ----------------
__global__ __launch_bounds__(256) void k4_mfma(
    const float* __restrict__ Y2, const float* __restrict__ scale2,
    const float* __restrict__ shift2, const ushort* __restrict__ W3hi,
    const ushort* __restrict__ W3lo, float* __restrict__ Y3) {
  __shared__ short lAhi[32 * 64], lAlo[32 * 64];
  int b0 = blockIdx.x * 32;
  int kb = blockIdx.y * 128;
  int tid = threadIdx.x;
  int lane = tid & 63, wave = tid >> 6;
  int wm = wave & 1, wn = wave >> 1;
  f32x4 acc[5] = {};
  int srow = tid >> 3, sch = tid & 7;
  for (int k0 = 0; k0 < 128; k0 += 64) {
    int kg = kb + k0 + sch * 8;
    const float* src = &Y2[(size_t)(b0 + srow) * 1024 + kg];
    float4 f0 = *(const float4*)src;
    float4 f1 = *(const float4*)(src + 4);
    float4 c0 = *(const float4*)&scale2[kg];
    float4 c1 = *(const float4*)&scale2[kg + 4];
    float4 s0 = *(const float4*)&shift2[kg];
    float4 s1 = *(const float4*)&shift2[kg + 4];
    float e[8] = {f0.x, f0.y, f0.z, f0.w, f1.x, f1.y, f1.z, f1.w};
    float cs[8] = {c0.x, c0.y, c0.z, c0.w, c1.x, c1.y, c1.z, c1.w};
    float sh[8] = {s0.x, s0.y, s0.z, s0.w, s1.x, s1.y, s1.z, s1.w};
    bf16x8 hh, ll;
#pragma unroll
    for (int q = 0; q < 8; ++q) {
      float x = fmaxf(0.f, fmaf(e[q], cs[q], sh[q]));
      short h, l;
      split2(x, h, l);
      hh[q] = h;
      ll[q] = l;
    }
    if (k0) __syncthreads();
    int d = srow * 64 + ((sch ^ (srow & 7)) << 3);
    *(bf16x8*)&lAhi[d] = hh;
    *(bf16x8*)&lAlo[d] = ll;
    __syncthreads();
#pragma unroll
    for (int kk = 0; kk < 2; ++kk) {
      int r = wm * 16 + (lane & 15);
      int ch = kk * 4 + (lane >> 4);
      int ad = r * 64 + ((ch ^ (r & 7)) << 3);
      bf16x8 ah = *(const bf16x8*)&lAhi[ad];
      bf16x8 al = *(const bf16x8*)&lAlo[ad];
#pragma unroll
      for (int ni = 0; ni < 5; ++ni) {
        int col = wn * 80 + ni * 16 + (lane & 15);
        size_t wo = (size_t)col * 1024 + kb + k0 + kk * 32 + (lane >> 4) * 8;
        bf16x8 bh = *(const bf16x8*)&W3hi[wo];
        bf16x8 bl = *(const bf16x8*)&W3lo[wo];
        acc[ni] = __builtin_amdgcn_mfma_f32_16x16x32_bf16(ah, bh, acc[ni], 0, 0, 0);
        acc[ni] = __builtin_amdgcn_mfma_f32_16x16x32_bf16(al, bh, acc[ni], 0, 0, 0);
        acc[ni] = __builtin_amdgcn_mfma_f32_16x16x32_bf16(ah, bl, acc[ni], 0, 0, 0);
      }
    }
  }
#pragma unroll
  for (int ni = 0; ni < 5; ++ni) {
    int col = wn * 80 + ni * 16 + (lane & 15);
    if (col < 150) {
#pragma unroll
      for (int r = 0; r < 4; ++r) {
        int row = b0 + wm * 16 + (lane >> 4) * 4 + r;
        atomicAdd(&Y3[(size_t)row * 150 + col], acc[ni][r]);
      }
    }
  }
}

// ---------------- k5s: raw Y3 column stats -> atomic accumulators ----------------
__global__ __launch_bounds__(256) void k5s(const float* __restrict__ Y3,
                                           float* __restrict__ sA3,
                                           float* __restrict__ qA3) {
  int r0 = blockIdx.x * 8;
  int j = threadIdx.x;
  if (j >= 150) return;
  float s = 0.f, q = 0.f;
  for (int r = 0; r < 8; ++r) {
    float v = Y3[(size_t)(r0 + r) * 150 + j];
    s += v;
    q += v * v;
  }
  atomicAdd(&sA3[j], s);
  atomicAdd(&qA3[j], q);
}

// ---------------- k6a: BN3+ReLU + ct1 + composite(ct2*ct3*cf) -> pre-struct ----------------
__global__ __launch_bounds__(256) void k6a(
    const float* __restrict__ Y3, const float* __restrict__ sA3,
    const float* __restrict__ qA3, const float* __restrict__ g3,
    const float* __restrict__ be3, const float* __restrict__ ct1_w,
    const float* __restrict__ ct1_b, const float* __restrict__ ct2_w,
    const float* __restrict__ ct2_b, const float* __restrict__ ct3_w,
    const float* __restrict__ ct3_b, const float* __restrict__ cf_w,
    const float* __restrict__ cf_b, float* __restrict__ Spre) {
  __shared__ float wt1[32], wb1[4], wt2L[80], wb2L[4], w3fL[20];
  __shared__ float Cc[36], cfb2C[1], cfbraw[1];
  __shared__ float h0p[4][160];
  __shared__ float hA[4][4][312];
  __shared__ float Srow[4][304];
  int tid = threadIdx.x;
  if (tid < 32) wt1[tid] = ct1_w[tid];
  else if (tid < 36) wb1[tid - 32] = ct1_b[tid - 32];
  else if (tid < 116) wt2L[tid - 36] = ct2_w[tid - 36];
  else if (tid < 120) wb2L[tid - 116] = ct2_b[tid - 116];
  else if (tid < 140) {
    int i = (tid - 120) / 5, j = (tid - 120) % 5;
    float s = 0.f;
#pragma unroll
    for (int p = 0; p < 4; ++p) s += cf_w[p] * ct3_w[(i * 4 + p) * 5 + j];
    w3fL[tid - 120] = s;
  } else if (tid == 140) {
    float s = cf_b[0];
#pragma unroll
    for (int p = 0; p < 4; ++p) s += cf_w[p] * ct3_b[p];
    cfbraw[0] = s;
  }
  int w = tid >> 6;
  int lane = tid & 63;
  int r = blockIdx.x * 4 + w;
  for (int i = lane; i < 160; i += 64) {
    int k = i - 2;
    float v = 0.f;
    if (k >= 0 && k < 150) {
      float sc, sh;
      bn_coef(sA3[k], qA3[k], g3[k], be3[k], sc, sh);
      v = fmaxf(0.f, Y3[(size_t)r * 150 + k] * sc + sh);
    }
    h0p[w][i] = v;
  }
  if (lane < 12) {
    int z = (lane < 4) ? lane : (300 + lane);
#pragma unroll
    for (int o = 0; o < 4; ++o) hA[w][o][z] = 0.f;
  }
  __syncthreads();
  if (tid < 36) {
    int i = tid / 9, u = tid % 9;
    float s = 0.f;
#pragma unroll
    for (int o = 0; o < 4; ++o) {
      int j2lo = (u > 4) ? (u - 4) : 0;
      int j2hi = (u < 4) ? u : 4;
      for (int j2 = j2lo; j2 <= j2hi; ++j2)
        s += wt2L[(i * 4 + o) * 5 + (u - j2)] * w3fL[o * 5 + j2];
    }
    Cc[tid] = s;
  } else if (tid == 36) {
    float s = cfbraw[0];
#pragma unroll
    for (int o = 0; o < 4; ++o) {
      float t = 0.f;
#pragma unroll
      for (int j2 = 0; j2 < 5; ++j2) t += w3fL[o * 5 + j2];
      s += wb2L[o] * t;
    }
    cfb2C[0] = s;
  }
  __syncthreads();
  for (int t = lane; t < 300; t += 64) {
    int p1 = (t + 3) & 1;
    int base = (t + 3 - p1) >> 1;
    float x0 = h0p[w][2 + base];
    float x1 = h0p[w][1 + base];
    float x2 = h0p[w][base];
    float x3 = h0p[w][base - 1];
#pragma unroll
    for (int o = 0; o < 4; ++o) {
      float acc = wb1[o];
      acc += wt1[o * 8 + p1] * x0;
      acc += wt1[o * 8 + p1 + 2] * x1;
      acc += wt1[o * 8 + p1 + 4] * x2;
      acc += wt1[o * 8 + p1 + 6] * x3;
      hA[w][o][4 + t] = acc;
    }
  }
  __syncthreads();
  for (int t = lane; t < 300; t += 64) {
    float acc = cfb2C[0];
#pragma unroll
    for (int i = 0; i < 4; ++i)
#pragma unroll
      for (int u = 0; u < 9; ++u) acc += Cc[i * 9 + u] * hA[w][i][t + 8 - u];
    if (t < 2) {
      for (int j2 = t + 3; j2 <= 4; ++j2) {
        int tp_ = t + 2 - j2;
        float corr = 0.f;
        for (int o = 0; o < 4; ++o) {
          float hb = wb2L[o];
          for (int i2 = 0; i2 < 4; ++i2)
            for (int j1 = 0; j1 < 5; ++j1)
              hb += wt2L[(i2 * 4 + o) * 5 + j1] * hA[w][i2][6 + tp_ - j1];
          corr += w3fL[o * 5 + j2] * hb;
        }
        acc -= corr;
      }
    }
    if (t > 297) {
      for (int j2 = 0; j2 <= t - 298; ++j2) {
        int tp_ = t + 2 - j2;
        float corr = 0.f;
        for (int o = 0; o < 4; ++o) {
          float hb = wb2L[o];
          for (int i2 = 0; i2 < 4; ++i2)
            for (int j1 = 0; j1 < 5; ++j1)
              hb += wt2L[(i2 * 4 + o) * 5 + j1] * hA[w][i2][6 + tp_ - j1];
          corr += w3fL[o * 5 + j2] * hb;
        }
        acc -= corr;
      }
    }
    Srow[w][t] = acc;
  }
  __syncthreads();
  for (int cc = lane; cc < 100; cc += 64) {
    float s0 = Srow[w][3 * cc], s1 = Srow[w][3 * cc + 1], s2 = Srow[w][3 * cc + 2];
    float4 p;
    p.x = s0 * s0;
    p.y = s1 * s1;
    p.z = s2 * s2;
    p.w = 0.f;
    *(float4*)&Spre[((size_t)r * 100 + cc) * 4] = p;
  }
}

// ---------------- k6b: lorentz, cc-split x4, LDS broadcast ----------------
__global__ __launch_bounds__(320) void k6b(const float* __restrict__ Spre,
                                           float* __restrict__ out) {
  __shared__ float4 sp[25];
  int b = blockIdx.x;
  int l = threadIdx.x;
  const float4* pp = (const float4*)&Spre[(size_t)b * 400] + blockIdx.y * 25;
  if (l < 25) sp[l] = pp[l];
  __syncthreads();
  float wl = 0.8f + (float)l * (1.0f / 300.0f);
  float w2l = wl * wl;
  float acc = 0.f;
#pragma unroll 5
  for (int cc = 0; cc < 25; ++cc) {
    float4 p = sp[cc];
    float wp2 = p.x, s1sq = p.y, s2sq = p.z;
    float sub1 = s1sq - w2l;
    float denom = fmaf(sub1, sub1, w2l * s2sq);
    float inv = __builtin_amdgcn_rcpf(denom);
    float u = wp2 * inv;
    float tp = u * (wp2 + sub1);
    float tm = u * (wp2 - sub1);
    float n = 0.70710678f * __builtin_amdgcn_sqrtf(fmaxf(tp, 0.f));
    float np1 = n + 1.0f;
    float den2 = fmaf(np1, np1, 0.5f * fmaxf(tm, 0.f));
    acc = fmaf(4.0f * n, __builtin_amdgcn_rcpf(den2), acc);
  }
  if (l < 300) atomicAdd(&out[(size_t)b * 300 + l], acc);
}

extern "C" void kernel_launch(void* const* d_in, const int* in_sizes, int n_in,
                              void* d_out, int out_size, void* d_ws,
                              size_t ws_size, hipStream_t stream) {
  const float* G = (const float*)d_in[0];
  const float* w1 = (const float*)d_in[1];
  const float* g1 = (const float*)d_in[3];
  const float* be1 = (const float*)d_in[4];
  const float* w2 = (const float*)d_in[5];
  const float* g2 = (const float*)d_in[7];
  const float* be2 = (const float*)d_in[8];
  const float* w3 = (const float*)d_in[9];
  const float* g3 = (const float*)d_in[11];
  const float* be3 = (const float*)d_in[12];
  const float* ct1_w = (const float*)d_in[13];
  const float* ct1_b = (const float*)d_in[14];
  const float* ct2_w = (const float*)d_in[15];
  const float* ct2_b = (const float*)d_in[16];
  const float* ct3_w = (const float*)d_in[17];
  const float* ct3_b = (const float*)d_in[18];
  const float* cf_w = (const float*)d_in[19];
  const float* cf_b = (const float*)d_in[20];
  float* out = (float*)d_out;

  float* ws = (float*)d_ws;
  float* Y2 = ws;                             // [0, 2097152)
  ushort* X1thi = (ushort*)(ws + 2097152);    // tiled-swizzled
  ushort* W3hi = (ushort*)(ws + 2097152);     // after k2
  ushort* W3lo = (ushort*)(ws + 2179072);
  float* scale2 = ws + 2260992;
  float* shift2 = ws + 2262016;
  float* Spre = ws + 2097152;                 // after k4
  ushort* X1tlo = (ushort*)(ws + 3145728);
  float* Y3 = ws + 3887104;
  float* sA1 = ws + 4194304;
  float* qA1 = sA1 + 1024;
  float* sA2 = sA1 + 2048;
  float* qA2 = sA1 + 3072;
  float* sA3 = sA1 + 4096;
  float* qA3 = sA1 + 4288;
  ushort* W2thi = (ushort*)(ws + 4198752);    // 1M ushorts
  ushort* W2tlo = (ushort*)(ws + 4723040);    // 1M ushorts

  k2w<<<1024, 256, 0, stream>>>(w2, W2thi, W2tlo);
  kzero0<<<605, 256, 0, stream>>>((float4*)out, (float4*)sA1);
  k1s<<<256, 256, 0, stream>>>(G, w1, sA1, qA1);
  k1c<<<256, 256, 0, stream>>>(G, w1, sA1, qA1, g1, be1, X1thi, X1tlo);
  k2_mfma<<<256, 512, 0, stream>>>(X1thi, X1tlo, W2thi, W2tlo, Y2, sA2, qA2);
  k4w<<<461, 256, 0, stream>>>(w3, sA2, qA2, g2, be2, W3hi, W3lo, scale2,
                               shift2, (float4*)Y3);
  k4_mfma<<<dim3(64, 8), 256, 0, stream>>>(Y2, scale2, shift2, W3hi, W3lo, Y3);
  k5s<<<256, 256, 0, stream>>>(Y3, sA3, qA3);
  k6a<<<512, 256, 0, stream>>>(Y3, sA3, qA3, g3, be3, ct1_w, ct1_b, ct2_w,
                               ct2_b, ct3_w, ct3_b, cf_w, cf_b, Spre);
  k6b<<<dim3(2048, 4), 320, 0, stream>>>(Spre, out);
}